// Round 3
// baseline (314.077 us; speedup 1.0000x reference)
//
#include <hip/hip_runtime.h>

#define EMB 1024
#define NSEQ 2048
#define NBATCH 2
#define NHEAD 16
#define DHEAD 64
// 0.125 (attn scale) * log2(e), folded into Q at projection time; attn uses exp2
#define QSCALE 0.18033688011112042f

typedef float f32x4 __attribute__((ext_vector_type(4)));
typedef short s16x8 __attribute__((ext_vector_type(8)));
typedef short s16x4 __attribute__((ext_vector_type(4)));

typedef __attribute__((address_space(3))) short lds_short;
typedef __attribute__((address_space(1))) const short glb_short;

__device__ __forceinline__ void gl_lds16(const short* g, short* l) {
    __builtin_amdgcn_global_load_lds((glb_short*)g, (lds_short*)l, 16, 0, 0);
}

__device__ __forceinline__ short bf16r(float f) {
    unsigned u = __float_as_uint(f);
    u += 0x7fffu + ((u >> 16) & 1u);
    return (short)(u >> 16);
}

__device__ __forceinline__ unsigned pkbf(float a, float b) {
#if defined(__has_builtin) && __has_builtin(__builtin_amdgcn_cvt_pk_bf16_f32)
    auto r = __builtin_amdgcn_cvt_pk_bf16_f32(a, b);
    unsigned u;
    __builtin_memcpy(&u, &r, 4);
    return u;
#else
    return ((unsigned)bf16r(a) & 0xffffu) | ((unsigned)bf16r(b) << 16);
#endif
}

__device__ __forceinline__ float fexp2(float x) {
#if defined(__has_builtin) && __has_builtin(__builtin_amdgcn_exp2f)
    return __builtin_amdgcn_exp2f(x);
#else
    return exp2f(x);
#endif
}

// ---------------------------------------------------------------------------
// fp32 -> bf16 conversion pass (memory-bound). grid.y = segment 0..5.
// ---------------------------------------------------------------------------
__global__ __launch_bounds__(256) void cvt6_kernel(
    const float* __restrict__ s0, const float* __restrict__ s1, const float* __restrict__ s2,
    const float* __restrict__ s3, const float* __restrict__ s4, const float* __restrict__ s5,
    short* __restrict__ d0, short* __restrict__ d1, short* __restrict__ d2,
    short* __restrict__ d3, short* __restrict__ d4, short* __restrict__ d5,
    int n0, int n1, int n2, int n3, int n4, int n5)
{
    const int seg = blockIdx.y;
    const float* s = (seg == 0) ? s0 : (seg == 1) ? s1 : (seg == 2) ? s2
                   : (seg == 3) ? s3 : (seg == 4) ? s4 : s5;
    short* d = (seg == 0) ? d0 : (seg == 1) ? d1 : (seg == 2) ? d2
             : (seg == 3) ? d3 : (seg == 4) ? d4 : d5;
    const int n = (seg == 0) ? n0 : (seg == 1) ? n1 : (seg == 2) ? n2
                : (seg == 3) ? n3 : (seg == 4) ? n4 : n5;

    const int i = (blockIdx.x * 256 + threadIdx.x) * 8;
    if (i >= n) return;
    float4 a = *(const float4*)(s + i);
    float4 b = *(const float4*)(s + i + 4);
    uint4 u = { pkbf(a.x, a.y), pkbf(a.z, a.w), pkbf(b.x, b.y), pkbf(b.z, b.w) };
    *(uint4*)(d + i) = u;
}

// ---------------------------------------------------------------------------
// proj2: bf16 NT GEMM. 128x128 tile, BK=64, 4 waves x 64x64 quadrant.
// global_load_lds width=16 into UNPADDED LDS, XOR chunk swizzle (^ row&7).
// z==2 (V projection) writes the TRANSPOSED VT layout directly (kills vtrans).
// ---------------------------------------------------------------------------
__global__ __launch_bounds__(256, 3) void proj2_kernel(
    const short* __restrict__ Xq, const short* __restrict__ Xk, const short* __restrict__ Xv,
    const short* __restrict__ Wq, const short* __restrict__ Wk, const short* __restrict__ Wv,
    const float* __restrict__ bq, const float* __restrict__ bk, const float* __restrict__ bv,
    short* __restrict__ Oq, short* __restrict__ Ok, short* __restrict__ Ov)
{
    const int z = blockIdx.z;
    const short* X    = (z == 0) ? Xq : (z == 1) ? Xk : Xv;
    const short* W    = (z == 0) ? Wq : (z == 1) ? Wk : Wv;
    const float* bias = (z == 0) ? bq : (z == 1) ? bk : bv;
    short* Out        = (z == 0) ? Oq : (z == 1) ? Ok : Ov;
    const float osc   = (z == 0) ? QSCALE : 1.0f;

    const int n0 = blockIdx.x * 128;
    const int m0 = blockIdx.y * 128;

    __shared__ __align__(16) short As[128 * 64];
    __shared__ __align__(16) short Bs[128 * 64];

    const int t    = threadIdx.x;
    const int lane = t & 63;
    const int wave = t >> 6;
    const int r    = lane & 15;
    const int quad = lane >> 4;
    const int wm   = (wave >> 1) * 64;
    const int wn   = (wave & 1) * 64;

    const int p0    = wave * 256 + lane;
    const int row0  = p0 >> 3;
    const int lc0   = (p0 & 7) ^ (row0 & 7);
    const short* gA = X + (size_t)(m0 + row0) * EMB + lc0 * 8;
    const short* gB = W + (size_t)(n0 + row0) * EMB + lc0 * 8;
    short* lA = As + p0 * 8;
    short* lB = Bs + p0 * 8;

    f32x4 acc[4][4];
#pragma unroll
    for (int i = 0; i < 4; ++i)
#pragma unroll
        for (int j = 0; j < 4; ++j)
#pragma unroll
            for (int v = 0; v < 4; ++v) acc[i][j][v] = 0.f;

    for (int k0 = 0; k0 < EMB; k0 += 64) {
#pragma unroll
        for (int i = 0; i < 4; ++i) {
            gl_lds16(gA + k0 + (size_t)8 * i * EMB, lA + i * 512);
            gl_lds16(gB + k0 + (size_t)8 * i * EMB, lB + i * 512);
        }
        __syncthreads();

#pragma unroll
        for (int ks = 0; ks < 2; ++ks) {
            const int fc = ((ks * 4 + quad) ^ (r & 7)) * 8;
            s16x8 af[4], bf[4];
#pragma unroll
            for (int i = 0; i < 4; ++i) af[i] = *(const s16x8*)&As[(wm + i * 16 + r) * 64 + fc];
#pragma unroll
            for (int j = 0; j < 4; ++j) bf[j] = *(const s16x8*)&Bs[(wn + j * 16 + r) * 64 + fc];
#pragma unroll
            for (int i = 0; i < 4; ++i)
#pragma unroll
                for (int j = 0; j < 4; ++j)
                    acc[i][j] = __builtin_amdgcn_mfma_f32_16x16x32_bf16(af[i], bf[j], acc[i][j], 0, 0, 0);
        }
        __syncthreads();
    }

    if (z != 2) {
#pragma unroll
        for (int j = 0; j < 4; ++j) {
            const int gn = n0 + wn + j * 16 + r;
            const float bb = bias[gn];
#pragma unroll
            for (int i = 0; i < 4; ++i)
#pragma unroll
                for (int reg = 0; reg < 4; ++reg) {
                    const int gm = m0 + wm + i * 16 + quad * 4 + reg;
                    Out[(size_t)gm * EMB + gn] = bf16r((acc[i][j][reg] + bb) * osc);
                }
        }
    } else {
        // V: write VT[(b*16+h)*64+d][token] directly.  gn -> (h,d), gm -> (b,token).
#pragma unroll
        for (int j = 0; j < 4; ++j) {
            const int gn = n0 + wn + j * 16 + r;
            const float bb = bias[gn];
            const int hh = gn >> 6;
            const int dd = gn & 63;
#pragma unroll
            for (int i = 0; i < 4; ++i) {
                const int gm = m0 + wm + i * 16 + quad * 4;
                const int bi = gm >> 11;
                const int nn = gm & 2047;
                s16x4 pk;
#pragma unroll
                for (int reg = 0; reg < 4; ++reg) pk[reg] = bf16r(acc[i][j][reg] + bb);
                *(s16x4*)(Out + ((size_t)(bi * NHEAD + hh) * DHEAD + dd) * NSEQ + nn) = pk;
            }
        }
    }
}

// ---------------------------------------------------------------------------
// Fallback projection (fp32 inputs, convert during staging). Row-major outputs.
// ---------------------------------------------------------------------------
__global__ __launch_bounds__(256) void proj_kernel(
    const float* __restrict__ Xq, const float* __restrict__ Xk, const float* __restrict__ Xv,
    const float* __restrict__ Wq, const float* __restrict__ Wk, const float* __restrict__ Wv,
    const float* __restrict__ bq, const float* __restrict__ bk, const float* __restrict__ bv,
    short* __restrict__ Oq, short* __restrict__ Ok, short* __restrict__ Ov)
{
    const int z = blockIdx.z;
    const float* X    = (z == 0) ? Xq : (z == 1) ? Xk : Xv;
    const float* W    = (z == 0) ? Wq : (z == 1) ? Wk : Wv;
    const float* bias = (z == 0) ? bq : (z == 1) ? bk : bv;
    short* Out        = (z == 0) ? Oq : (z == 1) ? Ok : Ov;
    const float osc   = (z == 0) ? QSCALE : 1.0f;

    const int n0 = blockIdx.x * 128;
    const int m0 = blockIdx.y * 128;

    __shared__ __align__(16) short As[128][40];
    __shared__ __align__(16) short Bs[128][40];

    const int t    = threadIdx.x;
    const int lane = t & 63;
    const int wave = t >> 6;
    const int r    = lane & 15;
    const int quad = lane >> 4;
    const int wm   = (wave >> 1) * 64;
    const int wn   = (wave & 1) * 64;

    const int srow = t >> 1;
    const int scol = (t & 1) << 4;

    f32x4 acc[4][4];
#pragma unroll
    for (int i = 0; i < 4; ++i)
#pragma unroll
        for (int j = 0; j < 4; ++j)
#pragma unroll
            for (int v = 0; v < 4; ++v) acc[i][j][v] = 0.f;

    for (int k0 = 0; k0 < EMB; k0 += 32) {
        const float4* xp = (const float4*)(X + (size_t)(m0 + srow) * EMB + k0 + scol);
        const float4* wp = (const float4*)(W + (size_t)(n0 + srow) * EMB + k0 + scol);
        float4 x0 = xp[0], x1 = xp[1], x2 = xp[2], x3 = xp[3];
        float4 w0 = wp[0], w1 = wp[1], w2 = wp[2], w3 = wp[3];
        uint4 a0 = { pkbf(x0.x, x0.y), pkbf(x0.z, x0.w), pkbf(x1.x, x1.y), pkbf(x1.z, x1.w) };
        uint4 a1 = { pkbf(x2.x, x2.y), pkbf(x2.z, x2.w), pkbf(x3.x, x3.y), pkbf(x3.z, x3.w) };
        uint4 b0 = { pkbf(w0.x, w0.y), pkbf(w0.z, w0.w), pkbf(w1.x, w1.y), pkbf(w1.z, w1.w) };
        uint4 b1 = { pkbf(w2.x, w2.y), pkbf(w2.z, w2.w), pkbf(w3.x, w3.y), pkbf(w3.z, w3.w) };
        *(uint4*)&As[srow][scol]     = a0;
        *(uint4*)&As[srow][scol + 8] = a1;
        *(uint4*)&Bs[srow][scol]     = b0;
        *(uint4*)&Bs[srow][scol + 8] = b1;
        __syncthreads();

        s16x8 af[4], bf[4];
#pragma unroll
        for (int i = 0; i < 4; ++i) af[i] = *(const s16x8*)&As[wm + i * 16 + r][quad * 8];
#pragma unroll
        for (int j = 0; j < 4; ++j) bf[j] = *(const s16x8*)&Bs[wn + j * 16 + r][quad * 8];
#pragma unroll
        for (int i = 0; i < 4; ++i)
#pragma unroll
            for (int j = 0; j < 4; ++j)
                acc[i][j] = __builtin_amdgcn_mfma_f32_16x16x32_bf16(af[i], bf[j], acc[i][j], 0, 0, 0);
        __syncthreads();
    }

#pragma unroll
    for (int j = 0; j < 4; ++j) {
        const int gn = n0 + wn + j * 16 + r;
        const float bb = bias[gn];
#pragma unroll
        for (int i = 0; i < 4; ++i)
#pragma unroll
            for (int reg = 0; reg < 4; ++reg) {
                const int gm = m0 + wm + i * 16 + quad * 4 + reg;
                Out[(size_t)gm * EMB + gn] = bf16r((acc[i][j][reg] + bb) * osc);
            }
    }
}

// ---------------------------------------------------------------------------
// V transpose (fallback path only): V [b*2048+n][h*64+d] -> VT [(b*16+h)*64+d][n]
// ---------------------------------------------------------------------------
__global__ __launch_bounds__(256) void vtrans_kernel(
    const short* __restrict__ Vp, short* __restrict__ VT)
{
    const int n0 = blockIdx.x * 64;
    const int h  = blockIdx.y;
    const int b  = blockIdx.z;
    __shared__ __align__(16) short L[64][72];

    const int t  = threadIdx.x;
    const int rr = t >> 2;
    const int cc = (t & 3) * 16;

    const short* src = Vp + (size_t)(b * NSEQ + n0 + rr) * EMB + h * DHEAD + cc;
    s16x8 a = *(const s16x8*)src;
    s16x8 c = *(const s16x8*)(src + 8);
    *(s16x8*)&L[rr][cc]     = a;
    *(s16x8*)&L[rr][cc + 8] = c;
    __syncthreads();

    const int d  = t >> 2;
    const int c4 = (t & 3) * 16;
    short vals[16];
#pragma unroll
    for (int i = 0; i < 16; ++i) vals[i] = L[c4 + i][d];
    short* dst = VT + ((size_t)(b * NHEAD + h) * DHEAD + d) * NSEQ + n0 + c4;
    *(s16x8*)dst       = *(s16x8*)&vals[0];
    *(s16x8*)(dst + 8) = *(s16x8*)&vals[8];
}

// ---------------------------------------------------------------------------
// attn10: attn7 structure (256 thr, 4 waves x 32 q-rows, K-tile 128 keys,
// register prefetch, 2 barriers/tile) + XOR chunk-swizzled unpadded LDS
// (Ks[128][64] + Vs[64][128] = 32 KB) + setprio.  PARTIAL: key-split across
// BLOCKS (ksplit = blockIdx.x&1 handles 8 of 16 tiles), writing unnormalized
// f32 partial O + row-sums; grid 1024 -> 4 blocks/CU = 4 waves/SIMD with
// attn7's per-wave register footprint (no spills, unlike the 8-wave attn9).
// ---------------------------------------------------------------------------
template<bool PARTIAL>
__global__ __launch_bounds__(256, 4) void attn10_kernel(
    const short* __restrict__ Qp, const short* __restrict__ Kp,
    const short* __restrict__ VT, float* __restrict__ Outp,
    float* __restrict__ Lout)
{
    const int ksplit = PARTIAL ? (blockIdx.x & 1) : 0;
    const int qblk   = (PARTIAL ? (blockIdx.x >> 1) : blockIdx.x) * 128;
    const int h      = blockIdx.y;
    const int b      = blockIdx.z;
    const int nt     = PARTIAL ? 8 : 16;
    const int kt0    = PARTIAL ? ksplit * 8 : 0;

    __shared__ __align__(16) char smem[32768];
    short* Ks   = (short*)smem;               // [128][64] key x d, chunk-swizzled
    short* Vs   = (short*)smem + 128 * 64;    // [64][128] d x key, chunk-swizzled
    float* fbuf = (float*)smem;               // [64][68] floats (union, epilogue)

    const int t    = threadIdx.x;
    const int lane = t & 63;
    const int w    = t >> 6;         // q-strip: rows qblk + w*32 + qs*16 + r
    const int r    = lane & 15;
    const int quad = lane >> 4;
    const int r7   = r & 7;

    const size_t rowbase = (size_t)b * NSEQ;
    const int    colbase = h * DHEAD;
    const size_t bh64    = (size_t)(b * NHEAD + h) * DHEAD;

    // Q B-fragments
    s16x8 qf[2][2];
#pragma unroll
    for (int qs = 0; qs < 2; ++qs)
#pragma unroll
        for (int ks = 0; ks < 2; ++ks)
            qf[qs][ks] = *(const s16x8*)(Qp + (rowbase + qblk + w * 32 + qs * 16 + r) * EMB
                                          + colbase + ks * 32 + quad * 8);

    f32x4 accO[2][4];
#pragma unroll
    for (int qs = 0; qs < 2; ++qs)
#pragma unroll
        for (int dt = 0; dt < 4; ++dt)
#pragma unroll
            for (int v = 0; v < 4; ++v) accO[qs][dt][v] = 0.f;
    float lsum[2] = {0.f, 0.f};
    const f32x4 zf = {0.f, 0.f, 0.f, 0.f};

    // K staging: 128 rows x 8 chunks(16B); 2 threads/row, 4 chunks each
    const int krow = t >> 1;
    const int kc   = (t & 1) * 4;
    const short* gK = Kp + (rowbase + kt0 * 128 + krow) * EMB + colbase + kc * 8;
    short* lKb = Ks + krow * 64;
    int kch[4];
#pragma unroll
    for (int c = 0; c < 4; ++c) kch[c] = ((kc + c) ^ (krow & 7)) * 8;

    // V staging: 64 rows (d) x 16 chunks; 4 threads/row, 4 chunks each
    const int vrow = t >> 2;
    const int vc   = (t & 3) * 4;
    const short* gV = VT + (bh64 + vrow) * NSEQ + kt0 * 128 + vc * 8;
    short* lVb = Vs + vrow * 128;
    int vch[4];
#pragma unroll
    for (int c = 0; c < 4; ++c) vch[c] = ((vc + c) ^ (vrow & 7)) * 8;

    // read-side swizzled offsets (in shorts)
    const int kofs = (quad ^ r7) * 8;
    int vofs[4];
    {
        const int x4  = r7 & 4;
        const int qr3 = ((quad >> 1) ^ r7) & 3;
#pragma unroll
        for (int s = 0; s < 4; ++s)
            vofs[s] = ((((s << 2) ^ x4) | qr3) * 8) + (quad & 1) * 4;
    }

    // prologue: prefetch tile kt0 into registers
    s16x8 kr[4], vr[4];
#pragma unroll
    for (int c = 0; c < 4; ++c) {
        kr[c] = *(const s16x8*)(gK + c * 8);
        vr[c] = *(const s16x8*)(gV + c * 8);
    }
    const short* gKn = gK + (size_t)128 * EMB;
    const short* gVn = gV + 128;

    for (int it = 0; it < nt; ++it) {
        // write tile from registers (waits vmcnt on the prefetch)
#pragma unroll
        for (int c = 0; c < 4; ++c) {
            *(s16x8*)(lKb + kch[c]) = kr[c];
            *(s16x8*)(lVb + vch[c]) = vr[c];
        }
        __syncthreads();

        // issue prefetch of next tile — overlaps the compute below
        if (it + 1 < nt) {
#pragma unroll
            for (int c = 0; c < 4; ++c) {
                kr[c] = *(const s16x8*)(gKn + c * 8);
                vr[c] = *(const s16x8*)(gVn + c * 8);
            }
            gKn += (size_t)128 * EMB;
            gVn += 128;
        }

        // S^T = K Q^T per key-strip pair; exp2; pack PV B-fragments pf[qs][s]
        s16x8 pf[2][4];
#pragma unroll
        for (int s = 0; s < 4; ++s) {
            const short* kb = Ks + (s * 32 + r) * 64;
            const s16x8 kf00 = *(const s16x8*)(kb + kofs);
            const s16x8 kf01 = *(const s16x8*)(kb + (kofs ^ 32));
            const s16x8 kf10 = *(const s16x8*)(kb + 1024 + kofs);
            const s16x8 kf11 = *(const s16x8*)(kb + 1024 + (kofs ^ 32));
#pragma unroll
            for (int qs = 0; qs < 2; ++qs) {
                __builtin_amdgcn_s_setprio(1);
                f32x4 s0 = __builtin_amdgcn_mfma_f32_16x16x32_bf16(
                    kf01, qf[qs][1], __builtin_amdgcn_mfma_f32_16x16x32_bf16(kf00, qf[qs][0], zf, 0, 0, 0), 0, 0, 0);
                f32x4 s1 = __builtin_amdgcn_mfma_f32_16x16x32_bf16(
                    kf11, qf[qs][1], __builtin_amdgcn_mfma_f32_16x16x32_bf16(kf10, qf[qs][0], zf, 0, 0, 0), 0, 0, 0);
                __builtin_amdgcn_s_setprio(0);
                float p0[4], p1[4];
#pragma unroll
                for (int reg = 0; reg < 4; ++reg) {
                    p0[reg] = fexp2(s0[reg]);
                    p1[reg] = fexp2(s1[reg]);
                    lsum[qs] += p0[reg] + p1[reg];
                }
                uint4 uu = { pkbf(p0[0], p0[1]), pkbf(p0[2], p0[3]),
                             pkbf(p1[0], p1[1]), pkbf(p1[2], p1[3]) };
                __builtin_memcpy(&pf[qs][s], &uu, 16);
            }
        }

        // O^T += V^T P
#pragma unroll
        for (int dt = 0; dt < 4; ++dt) {
            const short* vb = Vs + (dt * 16 + r) * 128;
            s16x8 vfl[4];
#pragma unroll
            for (int s = 0; s < 4; ++s) {
                s16x4 lo = *(const s16x4*)(vb + vofs[s]);
                s16x4 hi = *(const s16x4*)(vb + (vofs[s] ^ 16));
                vfl[s] = __builtin_shufflevector(lo, hi, 0, 1, 2, 3, 4, 5, 6, 7);
            }
            __builtin_amdgcn_s_setprio(1);
#pragma unroll
            for (int qs = 0; qs < 2; ++qs)
#pragma unroll
                for (int s = 0; s < 4; ++s)
                    accO[qs][dt] = __builtin_amdgcn_mfma_f32_16x16x32_bf16(vfl[s], pf[qs][s], accO[qs][dt], 0, 0, 0);
            __builtin_amdgcn_s_setprio(0);
        }
        __syncthreads();
    }

    // row sums + (for PARTIAL) publish them
    float rl[2];
#pragma unroll
    for (int qs = 0; qs < 2; ++qs) {
        float s = lsum[qs];
        s += __shfl_xor(s, 16);
        s += __shfl_xor(s, 32);
        rl[qs] = PARTIAL ? 1.f : 1.f / s;
        if (PARTIAL && lane < 16)
            Lout[ksplit * (NBATCH * NHEAD * NSEQ)
                 + (b * NHEAD + h) * NSEQ + qblk + w * 32 + qs * 16 + r] = s;
    }
    float* Obase = PARTIAL
        ? Outp + (size_t)ksplit * ((size_t)NBATCH * NSEQ * EMB)
        : Outp;

    // Epilogue: O^T (rows=d, cols=q) -> fbuf[q][d] -> coalesced f32x4 stores
#pragma unroll
    for (int qs = 0; qs < 2; ++qs) {
        __syncthreads();
#pragma unroll
        for (int dt = 0; dt < 4; ++dt)
#pragma unroll
            for (int reg = 0; reg < 4; ++reg)
                fbuf[(w * 16 + r) * 68 + dt * 16 + quad * 4 + reg] = accO[qs][dt][reg] * rl[qs];
        __syncthreads();
        const int qi   = t >> 2;
        const int c    = (t & 3) * 16;
        const int wsrc = qi >> 4;
        const int rsrc = qi & 15;
        const float4* fp = (const float4*)&fbuf[(wsrc * 16 + rsrc) * 68 + c];
        float4 o0 = fp[0], o1 = fp[1], o2 = fp[2], o3 = fp[3];
        float* op = Obase + (rowbase + qblk + wsrc * 32 + qs * 16 + rsrc) * EMB + colbase + c;
        ((float4*)op)[0] = o0;
        ((float4*)op)[1] = o1;
        ((float4*)op)[2] = o2;
        ((float4*)op)[3] = o3;
    }
}

// ---------------------------------------------------------------------------
// combine: out = (O0 + O1) / (l0 + l1).  Pure-BW, ~50 MB.
// ---------------------------------------------------------------------------
__global__ __launch_bounds__(256) void comb_kernel(
    const float* __restrict__ O0, const float* __restrict__ O1,
    const float* __restrict__ L0, const float* __restrict__ L1,
    float* __restrict__ Out)
{
    const size_t i = ((size_t)blockIdx.x * 256 + threadIdx.x) * 4;
    const int b = (int)(i >> 21);              // NSEQ*EMB = 2^21
    const int q = (int)((i >> 10) & (NSEQ - 1));
    const int h = (int)((i >> 6) & (NHEAD - 1));
    const int li = (b * NHEAD + h) * NSEQ + q;
    const float rl = 1.f / (L0[li] + L1[li]);
    float4 a = *(const float4*)(O0 + i);
    float4 c = *(const float4*)(O1 + i);
    float4 o = { (a.x + c.x) * rl, (a.y + c.y) * rl, (a.z + c.z) * rl, (a.w + c.w) * rl };
    *(float4*)(Out + i) = o;
}

// ---------------------------------------------------------------------------
// Fallback attention (round-1 structure) for small ws.
// ---------------------------------------------------------------------------
__global__ __launch_bounds__(256) void attn_fb_kernel(
    const short* __restrict__ Qp, const short* __restrict__ Kp,
    const short* __restrict__ Vp, float* __restrict__ Out)
{
    const int qt = blockIdx.x;
    const int h  = blockIdx.y;
    const int b  = blockIdx.z;

    __shared__ __align__(16) short Ks[64][72];
    __shared__ __align__(16) short VsT[64][72];
    __shared__ __align__(16) short Ps[4][16][72];

    const int t    = threadIdx.x;
    const int lane = t & 63;
    const int w    = t >> 6;
    const int r    = lane & 15;
    const int quad = lane >> 4;

    const size_t rowbase = (size_t)b * NSEQ;
    const int colbase    = h * DHEAD;

    const short* Qr = Qp + (rowbase + qt * 64 + w * 16 + r) * EMB + colbase;
    const s16x8 qf0 = *(const s16x8*)(Qr + quad * 8);
    const s16x8 qf1 = *(const s16x8*)(Qr + 32 + quad * 8);

    float mrow[4], lrow[4];
    f32x4 accO[4];
#pragma unroll
    for (int i = 0; i < 4; ++i) {
        mrow[i] = -INFINITY;
        lrow[i] = 0.f;
#pragma unroll
        for (int v = 0; v < 4; ++v) accO[i][v] = 0.f;
    }

    const int srow = t >> 2;
    const int scol = (t & 3) << 4;

    for (int kt = 0; kt < 32; ++kt) {
        const short* Krow = Kp + (rowbase + kt * 64 + srow) * EMB + colbase + scol;
        const short* Vrow = Vp + (rowbase + kt * 64 + srow) * EMB + colbase + scol;
        s16x8 kv0 = *(const s16x8*)Krow;
        s16x8 kv1 = *(const s16x8*)(Krow + 8);
        s16x8 vv0 = *(const s16x8*)Vrow;
        s16x8 vv1 = *(const s16x8*)(Vrow + 8);
        *(s16x8*)&Ks[srow][scol]     = kv0;
        *(s16x8*)&Ks[srow][scol + 8] = kv1;
#pragma unroll
        for (int i = 0; i < 8; ++i) {
            VsT[scol + i][srow]     = vv0[i];
            VsT[scol + 8 + i][srow] = vv1[i];
        }
        __syncthreads();

        f32x4 sacc[4];
#pragma unroll
        for (int j = 0; j < 4; ++j) {
#pragma unroll
            for (int v = 0; v < 4; ++v) sacc[j][v] = 0.f;
            s16x8 kf0 = *(const s16x8*)&Ks[j * 16 + r][quad * 8];
            s16x8 kf1 = *(const s16x8*)&Ks[j * 16 + r][32 + quad * 8];
            sacc[j] = __builtin_amdgcn_mfma_f32_16x16x32_bf16(qf0, kf0, sacc[j], 0, 0, 0);
            sacc[j] = __builtin_amdgcn_mfma_f32_16x16x32_bf16(qf1, kf1, sacc[j], 0, 0, 0);
        }

        float rmax[4];
#pragma unroll
        for (int reg = 0; reg < 4; ++reg) rmax[reg] = -INFINITY;
#pragma unroll
        for (int j = 0; j < 4; ++j)
#pragma unroll
            for (int reg = 0; reg < 4; ++reg)
                rmax[reg] = fmaxf(rmax[reg], sacc[j][reg]);
#pragma unroll
        for (int reg = 0; reg < 4; ++reg) {
#pragma unroll
            for (int mask = 1; mask <= 8; mask <<= 1)
                rmax[reg] = fmaxf(rmax[reg], __shfl_xor(rmax[reg], mask, 64));
        }

        float alpha[4], rsum[4];
#pragma unroll
        for (int reg = 0; reg < 4; ++reg) {
            float mnew = fmaxf(mrow[reg], rmax[reg]);
            alpha[reg] = fexp2(mrow[reg] - mnew);
            mrow[reg]  = mnew;
            rsum[reg]  = 0.f;
        }

#pragma unroll
        for (int j = 0; j < 4; ++j)
#pragma unroll
            for (int reg = 0; reg < 4; ++reg) {
                float p = fexp2(sacc[j][reg] - mrow[reg]);
                rsum[reg] += p;
                Ps[w][quad * 4 + reg][j * 16 + r] = bf16r(p);
            }
#pragma unroll
        for (int reg = 0; reg < 4; ++reg) {
#pragma unroll
            for (int mask = 1; mask <= 8; mask <<= 1)
                rsum[reg] += __shfl_xor(rsum[reg], mask, 64);
            lrow[reg] = lrow[reg] * alpha[reg] + rsum[reg];
        }
#pragma unroll
        for (int j = 0; j < 4; ++j)
#pragma unroll
            for (int reg = 0; reg < 4; ++reg) accO[j][reg] *= alpha[reg];

#pragma unroll
        for (int s = 0; s < 2; ++s) {
            s16x8 pfr = *(const s16x8*)&Ps[w][r][s * 32 + quad * 8];
#pragma unroll
            for (int j = 0; j < 4; ++j) {
                s16x8 vfr = *(const s16x8*)&VsT[j * 16 + r][s * 32 + quad * 8];
                accO[j] = __builtin_amdgcn_mfma_f32_16x16x32_bf16(pfr, vfr, accO[j], 0, 0, 0);
            }
        }
        __syncthreads();
    }

#pragma unroll
    for (int j = 0; j < 4; ++j)
#pragma unroll
        for (int reg = 0; reg < 4; ++reg) {
            const int qrow = qt * 64 + w * 16 + quad * 4 + reg;
            Out[(rowbase + qrow) * EMB + colbase + j * 16 + r] = accO[j][reg] / lrow[reg];
        }
}

extern "C" void kernel_launch(void* const* d_in, const int* in_sizes, int n_in,
                              void* d_out, int out_size, void* d_ws, size_t ws_size,
                              hipStream_t stream) {
    const float* query = (const float*)d_in[0];
    const float* key   = (const float*)d_in[1];
    const float* value = (const float*)d_in[2];
    const float* Wq    = (const float*)d_in[3];
    const float* bq    = (const float*)d_in[4];
    const float* Wk    = (const float*)d_in[5];
    const float* bk    = (const float*)d_in[6];
    const float* Wv    = (const float*)d_in[7];
    const float* bv    = (const float*)d_in[8];
    float* out = (float*)d_out;

    const size_t XBUF = (size_t)NBATCH * NSEQ * EMB;   // 4 Mi elements
    const size_t WBUF = (size_t)EMB * EMB;
    const size_t LBUF = (size_t)NBATCH * NHEAD * NSEQ; // 64 Ki elements

    short* Qb  = (short*)d_ws;
    short* Kb  = Qb + XBUF;
    short* Vb  = Kb + XBUF;
    short* VTb = Vb + XBUF;
    short* Xqb = VTb + XBUF;
    short* Xkb = Xqb + XBUF;
    short* Xvb = Xkb + XBUF;
    short* Wqb = Xvb + XBUF;
    short* Wkb = Wqb + WBUF;
    short* Wvb = Wkb + WBUF;
    float* OP  = (float*)(Wvb + WBUF);   // [2][XBUF] f32 partial O
    float* LP  = OP + 2 * XBUF;          // [2][LBUF] f32 partial sums

    const size_t need_full  = (7 * XBUF + 3 * WBUF) * sizeof(short);
    const size_t need_split = need_full + (2 * XBUF + 2 * LBUF) * sizeof(float);
    const size_t need_attn  = 4 * XBUF * sizeof(short);

    if (ws_size >= need_split) {
        cvt6_kernel<<<dim3(2048, 6), 256, 0, stream>>>(
            query, key, value, Wq, Wk, Wv,
            Xqb, Xkb, Xvb, Wqb, Wkb, Wvb,
            (int)XBUF, (int)XBUF, (int)XBUF, (int)WBUF, (int)WBUF, (int)WBUF);
        proj2_kernel<<<dim3(EMB / 128, (NBATCH * NSEQ) / 128, 3), 256, 0, stream>>>(
            Xqb, Xkb, Xvb, Wqb, Wkb, Wvb, bq, bk, bv, Qb, Kb, VTb);
        attn10_kernel<true><<<dim3(2 * NSEQ / 128, NHEAD, NBATCH), 256, 0, stream>>>(
            Qb, Kb, VTb, OP, LP);
        comb_kernel<<<dim3((unsigned)(XBUF / 1024)), 256, 0, stream>>>(
            OP, OP + XBUF, LP, LP + LBUF, out);
    } else if (ws_size >= need_full) {
        cvt6_kernel<<<dim3(2048, 6), 256, 0, stream>>>(
            query, key, value, Wq, Wk, Wv,
            Xqb, Xkb, Xvb, Wqb, Wkb, Wvb,
            (int)XBUF, (int)XBUF, (int)XBUF, (int)WBUF, (int)WBUF, (int)WBUF);
        proj2_kernel<<<dim3(EMB / 128, (NBATCH * NSEQ) / 128, 3), 256, 0, stream>>>(
            Xqb, Xkb, Xvb, Wqb, Wkb, Wvb, bq, bk, bv, Qb, Kb, VTb);
        attn10_kernel<false><<<dim3(NSEQ / 128, NHEAD, NBATCH), 256, 0, stream>>>(
            Qb, Kb, VTb, out, nullptr);
    } else if (ws_size >= need_attn) {
        proj_kernel<<<dim3(EMB / 128, (NBATCH * NSEQ) / 128, 3), 256, 0, stream>>>(
            query, key, value, Wq, Wk, Wv, bq, bk, bv, Qb, Kb, Vb);
        vtrans_kernel<<<dim3(NSEQ / 64, NHEAD, NBATCH), 256, 0, stream>>>(Vb, VTb);
        attn10_kernel<false><<<dim3(NSEQ / 128, NHEAD, NBATCH), 256, 0, stream>>>(
            Qb, Kb, VTb, out, nullptr);
    } else {
        proj_kernel<<<dim3(EMB / 128, (NBATCH * NSEQ) / 128, 3), 256, 0, stream>>>(
            query, key, value, Wq, Wk, Wv, bq, bk, bv, Qb, Kb, Vb);
        attn_fb_kernel<<<dim3(NSEQ / 64, NHEAD, NBATCH), 256, 0, stream>>>(Qb, Kb, Vb, out);
    }
}

// Round 4
// 213.663 us; speedup vs baseline: 1.4700x; 1.4700x over previous
//
#include <hip/hip_runtime.h>

#define EMB 1024
#define NSEQ 2048
#define NBATCH 2
#define NHEAD 16
#define DHEAD 64
// 0.125 (attn scale) * log2(e), folded into Q at projection time; attn uses exp2
#define QSCALE 0.18033688011112042f

typedef float f32x4 __attribute__((ext_vector_type(4)));
typedef short s16x8 __attribute__((ext_vector_type(8)));
typedef short s16x4 __attribute__((ext_vector_type(4)));

typedef __attribute__((address_space(3))) short lds_short;
typedef __attribute__((address_space(1))) const short glb_short;

__device__ __forceinline__ void gl_lds16(const short* g, short* l) {
    __builtin_amdgcn_global_load_lds((glb_short*)g, (lds_short*)l, 16, 0, 0);
}

__device__ __forceinline__ short bf16r(float f) {
    unsigned u = __float_as_uint(f);
    u += 0x7fffu + ((u >> 16) & 1u);
    return (short)(u >> 16);
}

__device__ __forceinline__ unsigned pkbf(float a, float b) {
#if defined(__has_builtin) && __has_builtin(__builtin_amdgcn_cvt_pk_bf16_f32)
    auto r = __builtin_amdgcn_cvt_pk_bf16_f32(a, b);
    unsigned u;
    __builtin_memcpy(&u, &r, 4);
    return u;
#else
    return ((unsigned)bf16r(a) & 0xffffu) | ((unsigned)bf16r(b) << 16);
#endif
}

__device__ __forceinline__ float fexp2(float x) {
#if defined(__has_builtin) && __has_builtin(__builtin_amdgcn_exp2f)
    return __builtin_amdgcn_exp2f(x);
#else
    return exp2f(x);
#endif
}

// ---------------------------------------------------------------------------
// fp32 -> bf16 conversion pass (memory-bound). grid.y = segment 0..5.
// ---------------------------------------------------------------------------
__global__ __launch_bounds__(256) void cvt6_kernel(
    const float* __restrict__ s0, const float* __restrict__ s1, const float* __restrict__ s2,
    const float* __restrict__ s3, const float* __restrict__ s4, const float* __restrict__ s5,
    short* __restrict__ d0, short* __restrict__ d1, short* __restrict__ d2,
    short* __restrict__ d3, short* __restrict__ d4, short* __restrict__ d5,
    int n0, int n1, int n2, int n3, int n4, int n5)
{
    const int seg = blockIdx.y;
    const float* s = (seg == 0) ? s0 : (seg == 1) ? s1 : (seg == 2) ? s2
                   : (seg == 3) ? s3 : (seg == 4) ? s4 : s5;
    short* d = (seg == 0) ? d0 : (seg == 1) ? d1 : (seg == 2) ? d2
             : (seg == 3) ? d3 : (seg == 4) ? d4 : d5;
    const int n = (seg == 0) ? n0 : (seg == 1) ? n1 : (seg == 2) ? n2
                : (seg == 3) ? n3 : (seg == 4) ? n4 : n5;

    const int i = (blockIdx.x * 256 + threadIdx.x) * 8;
    if (i >= n) return;
    float4 a = *(const float4*)(s + i);
    float4 b = *(const float4*)(s + i + 4);
    uint4 u = { pkbf(a.x, a.y), pkbf(a.z, a.w), pkbf(b.x, b.y), pkbf(b.z, b.w) };
    *(uint4*)(d + i) = u;
}

// ---------------------------------------------------------------------------
// proj2: bf16 NT GEMM. 128x128 tile, BK=64, 4 waves x 64x64 quadrant.
// global_load_lds width=16 into UNPADDED LDS, XOR chunk swizzle (^ row&7).
// z==2 (V projection) writes the TRANSPOSED VT layout directly (kills vtrans).
// ---------------------------------------------------------------------------
__global__ __launch_bounds__(256, 3) void proj2_kernel(
    const short* __restrict__ Xq, const short* __restrict__ Xk, const short* __restrict__ Xv,
    const short* __restrict__ Wq, const short* __restrict__ Wk, const short* __restrict__ Wv,
    const float* __restrict__ bq, const float* __restrict__ bk, const float* __restrict__ bv,
    short* __restrict__ Oq, short* __restrict__ Ok, short* __restrict__ Ov)
{
    const int z = blockIdx.z;
    const short* X    = (z == 0) ? Xq : (z == 1) ? Xk : Xv;
    const short* W    = (z == 0) ? Wq : (z == 1) ? Wk : Wv;
    const float* bias = (z == 0) ? bq : (z == 1) ? bk : bv;
    short* Out        = (z == 0) ? Oq : (z == 1) ? Ok : Ov;
    const float osc   = (z == 0) ? QSCALE : 1.0f;

    const int n0 = blockIdx.x * 128;
    const int m0 = blockIdx.y * 128;

    __shared__ __align__(16) short As[128 * 64];
    __shared__ __align__(16) short Bs[128 * 64];

    const int t    = threadIdx.x;
    const int lane = t & 63;
    const int wave = t >> 6;
    const int r    = lane & 15;
    const int quad = lane >> 4;
    const int wm   = (wave >> 1) * 64;
    const int wn   = (wave & 1) * 64;

    const int p0    = wave * 256 + lane;
    const int row0  = p0 >> 3;
    const int lc0   = (p0 & 7) ^ (row0 & 7);
    const short* gA = X + (size_t)(m0 + row0) * EMB + lc0 * 8;
    const short* gB = W + (size_t)(n0 + row0) * EMB + lc0 * 8;
    short* lA = As + p0 * 8;
    short* lB = Bs + p0 * 8;

    f32x4 acc[4][4];
#pragma unroll
    for (int i = 0; i < 4; ++i)
#pragma unroll
        for (int j = 0; j < 4; ++j)
#pragma unroll
            for (int v = 0; v < 4; ++v) acc[i][j][v] = 0.f;

    for (int k0 = 0; k0 < EMB; k0 += 64) {
#pragma unroll
        for (int i = 0; i < 4; ++i) {
            gl_lds16(gA + k0 + (size_t)8 * i * EMB, lA + i * 512);
            gl_lds16(gB + k0 + (size_t)8 * i * EMB, lB + i * 512);
        }
        __syncthreads();

#pragma unroll
        for (int ks = 0; ks < 2; ++ks) {
            const int fc = ((ks * 4 + quad) ^ (r & 7)) * 8;
            s16x8 af[4], bf[4];
#pragma unroll
            for (int i = 0; i < 4; ++i) af[i] = *(const s16x8*)&As[(wm + i * 16 + r) * 64 + fc];
#pragma unroll
            for (int j = 0; j < 4; ++j) bf[j] = *(const s16x8*)&Bs[(wn + j * 16 + r) * 64 + fc];
#pragma unroll
            for (int i = 0; i < 4; ++i)
#pragma unroll
                for (int j = 0; j < 4; ++j)
                    acc[i][j] = __builtin_amdgcn_mfma_f32_16x16x32_bf16(af[i], bf[j], acc[i][j], 0, 0, 0);
        }
        __syncthreads();
    }

    if (z != 2) {
#pragma unroll
        for (int j = 0; j < 4; ++j) {
            const int gn = n0 + wn + j * 16 + r;
            const float bb = bias[gn];
#pragma unroll
            for (int i = 0; i < 4; ++i)
#pragma unroll
                for (int reg = 0; reg < 4; ++reg) {
                    const int gm = m0 + wm + i * 16 + quad * 4 + reg;
                    Out[(size_t)gm * EMB + gn] = bf16r((acc[i][j][reg] + bb) * osc);
                }
        }
    } else {
        // V: write VT[(b*16+h)*64+d][token] directly.  gn -> (h,d), gm -> (b,token).
#pragma unroll
        for (int j = 0; j < 4; ++j) {
            const int gn = n0 + wn + j * 16 + r;
            const float bb = bias[gn];
            const int hh = gn >> 6;
            const int dd = gn & 63;
#pragma unroll
            for (int i = 0; i < 4; ++i) {
                const int gm = m0 + wm + i * 16 + quad * 4;
                const int bi = gm >> 11;
                const int nn = gm & 2047;
                s16x4 pk;
#pragma unroll
                for (int reg = 0; reg < 4; ++reg) pk[reg] = bf16r(acc[i][j][reg] + bb);
                *(s16x4*)(Out + ((size_t)(bi * NHEAD + hh) * DHEAD + dd) * NSEQ + nn) = pk;
            }
        }
    }
}

// ---------------------------------------------------------------------------
// Fallback projection (fp32 inputs, convert during staging). Row-major outputs.
// ---------------------------------------------------------------------------
__global__ __launch_bounds__(256) void proj_kernel(
    const float* __restrict__ Xq, const float* __restrict__ Xk, const float* __restrict__ Xv,
    const float* __restrict__ Wq, const float* __restrict__ Wk, const float* __restrict__ Wv,
    const float* __restrict__ bq, const float* __restrict__ bk, const float* __restrict__ bv,
    short* __restrict__ Oq, short* __restrict__ Ok, short* __restrict__ Ov)
{
    const int z = blockIdx.z;
    const float* X    = (z == 0) ? Xq : (z == 1) ? Xk : Xv;
    const float* W    = (z == 0) ? Wq : (z == 1) ? Wk : Wv;
    const float* bias = (z == 0) ? bq : (z == 1) ? bk : bv;
    short* Out        = (z == 0) ? Oq : (z == 1) ? Ok : Ov;
    const float osc   = (z == 0) ? QSCALE : 1.0f;

    const int n0 = blockIdx.x * 128;
    const int m0 = blockIdx.y * 128;

    __shared__ __align__(16) short As[128][40];
    __shared__ __align__(16) short Bs[128][40];

    const int t    = threadIdx.x;
    const int lane = t & 63;
    const int wave = t >> 6;
    const int r    = lane & 15;
    const int quad = lane >> 4;
    const int wm   = (wave >> 1) * 64;
    const int wn   = (wave & 1) * 64;

    const int srow = t >> 1;
    const int scol = (t & 1) << 4;

    f32x4 acc[4][4];
#pragma unroll
    for (int i = 0; i < 4; ++i)
#pragma unroll
        for (int j = 0; j < 4; ++j)
#pragma unroll
            for (int v = 0; v < 4; ++v) acc[i][j][v] = 0.f;

    for (int k0 = 0; k0 < EMB; k0 += 32) {
        const float4* xp = (const float4*)(X + (size_t)(m0 + srow) * EMB + k0 + scol);
        const float4* wp = (const float4*)(W + (size_t)(n0 + srow) * EMB + k0 + scol);
        float4 x0 = xp[0], x1 = xp[1], x2 = xp[2], x3 = xp[3];
        float4 w0 = wp[0], w1 = wp[1], w2 = wp[2], w3 = wp[3];
        uint4 a0 = { pkbf(x0.x, x0.y), pkbf(x0.z, x0.w), pkbf(x1.x, x1.y), pkbf(x1.z, x1.w) };
        uint4 a1 = { pkbf(x2.x, x2.y), pkbf(x2.z, x2.w), pkbf(x3.x, x3.y), pkbf(x3.z, x3.w) };
        uint4 b0 = { pkbf(w0.x, w0.y), pkbf(w0.z, w0.w), pkbf(w1.x, w1.y), pkbf(w1.z, w1.w) };
        uint4 b1 = { pkbf(w2.x, w2.y), pkbf(w2.z, w2.w), pkbf(w3.x, w3.y), pkbf(w3.z, w3.w) };
        *(uint4*)&As[srow][scol]     = a0;
        *(uint4*)&As[srow][scol + 8] = a1;
        *(uint4*)&Bs[srow][scol]     = b0;
        *(uint4*)&Bs[srow][scol + 8] = b1;
        __syncthreads();

        s16x8 af[4], bf[4];
#pragma unroll
        for (int i = 0; i < 4; ++i) af[i] = *(const s16x8*)&As[wm + i * 16 + r][quad * 8];
#pragma unroll
        for (int j = 0; j < 4; ++j) bf[j] = *(const s16x8*)&Bs[wn + j * 16 + r][quad * 8];
#pragma unroll
        for (int i = 0; i < 4; ++i)
#pragma unroll
            for (int j = 0; j < 4; ++j)
                acc[i][j] = __builtin_amdgcn_mfma_f32_16x16x32_bf16(af[i], bf[j], acc[i][j], 0, 0, 0);
        __syncthreads();
    }

#pragma unroll
    for (int j = 0; j < 4; ++j) {
        const int gn = n0 + wn + j * 16 + r;
        const float bb = bias[gn];
#pragma unroll
        for (int i = 0; i < 4; ++i)
#pragma unroll
            for (int reg = 0; reg < 4; ++reg) {
                const int gm = m0 + wm + i * 16 + quad * 4 + reg;
                Out[(size_t)gm * EMB + gn] = bf16r((acc[i][j][reg] + bb) * osc);
            }
    }
}

// ---------------------------------------------------------------------------
// V transpose (fallback path only): V [b*2048+n][h*64+d] -> VT [(b*16+h)*64+d][n]
// ---------------------------------------------------------------------------
__global__ __launch_bounds__(256) void vtrans_kernel(
    const short* __restrict__ Vp, short* __restrict__ VT)
{
    const int n0 = blockIdx.x * 64;
    const int h  = blockIdx.y;
    const int b  = blockIdx.z;
    __shared__ __align__(16) short L[64][72];

    const int t  = threadIdx.x;
    const int rr = t >> 2;
    const int cc = (t & 3) * 16;

    const short* src = Vp + (size_t)(b * NSEQ + n0 + rr) * EMB + h * DHEAD + cc;
    s16x8 a = *(const s16x8*)src;
    s16x8 c = *(const s16x8*)(src + 8);
    *(s16x8*)&L[rr][cc]     = a;
    *(s16x8*)&L[rr][cc + 8] = c;
    __syncthreads();

    const int d  = t >> 2;
    const int c4 = (t & 3) * 16;
    short vals[16];
#pragma unroll
    for (int i = 0; i < 16; ++i) vals[i] = L[c4 + i][d];
    short* dst = VT + ((size_t)(b * NHEAD + h) * DHEAD + d) * NSEQ + n0 + c4;
    *(s16x8*)dst       = *(s16x8*)&vals[0];
    *(s16x8*)(dst + 8) = *(s16x8*)&vals[8];
}

// ---------------------------------------------------------------------------
// attn10: attn7 structure (256 thr, 4 waves x 32 q-rows, K-tile 128 keys,
// register prefetch, 2 barriers/tile) + XOR chunk-swizzled unpadded LDS
// (Ks[128][64] + Vs[64][128] = 32 KB) + setprio.  PARTIAL: key-split across
// BLOCKS (ksplit = blockIdx.x&1 handles 8 of 16 tiles), writing unnormalized
// f32 partial O + row-sums; grid 1024.
// launch_bounds (256,2): attn7's proven codegen (~108 regs, NO spill).
// (256,4) forced a 128-reg unified cap -> catastrophic scratch spill (R2/R3:
// 270MB FETCH + 400MB WRITE of spill traffic).  With ~110 regs + 32KB LDS,
// hardware occupancy reaches 4 blocks/CU on the 1024-block grid by itself.
// ---------------------------------------------------------------------------
template<bool PARTIAL>
__global__ __launch_bounds__(256, 2) void attn10_kernel(
    const short* __restrict__ Qp, const short* __restrict__ Kp,
    const short* __restrict__ VT, float* __restrict__ Outp,
    float* __restrict__ Lout)
{
    const int ksplit = PARTIAL ? (blockIdx.x & 1) : 0;
    const int qblk   = (PARTIAL ? (blockIdx.x >> 1) : blockIdx.x) * 128;
    const int h      = blockIdx.y;
    const int b      = blockIdx.z;
    const int nt     = PARTIAL ? 8 : 16;
    const int kt0    = PARTIAL ? ksplit * 8 : 0;

    __shared__ __align__(16) char smem[32768];
    short* Ks   = (short*)smem;               // [128][64] key x d, chunk-swizzled
    short* Vs   = (short*)smem + 128 * 64;    // [64][128] d x key, chunk-swizzled
    float* fbuf = (float*)smem;               // [64][68] floats (union, epilogue)

    const int t    = threadIdx.x;
    const int lane = t & 63;
    const int w    = t >> 6;         // q-strip: rows qblk + w*32 + qs*16 + r
    const int r    = lane & 15;
    const int quad = lane >> 4;
    const int r7   = r & 7;

    const size_t rowbase = (size_t)b * NSEQ;
    const int    colbase = h * DHEAD;
    const size_t bh64    = (size_t)(b * NHEAD + h) * DHEAD;

    // Q B-fragments
    s16x8 qf[2][2];
#pragma unroll
    for (int qs = 0; qs < 2; ++qs)
#pragma unroll
        for (int ks = 0; ks < 2; ++ks)
            qf[qs][ks] = *(const s16x8*)(Qp + (rowbase + qblk + w * 32 + qs * 16 + r) * EMB
                                          + colbase + ks * 32 + quad * 8);

    f32x4 accO[2][4];
#pragma unroll
    for (int qs = 0; qs < 2; ++qs)
#pragma unroll
        for (int dt = 0; dt < 4; ++dt)
#pragma unroll
            for (int v = 0; v < 4; ++v) accO[qs][dt][v] = 0.f;
    float lsum[2] = {0.f, 0.f};
    const f32x4 zf = {0.f, 0.f, 0.f, 0.f};

    // K staging: 128 rows x 8 chunks(16B); 2 threads/row, 4 chunks each
    const int krow = t >> 1;
    const int kc   = (t & 1) * 4;
    const short* gK = Kp + (rowbase + kt0 * 128 + krow) * EMB + colbase + kc * 8;
    short* lKb = Ks + krow * 64;
    int kch[4];
#pragma unroll
    for (int c = 0; c < 4; ++c) kch[c] = ((kc + c) ^ (krow & 7)) * 8;

    // V staging: 64 rows (d) x 16 chunks; 4 threads/row, 4 chunks each
    const int vrow = t >> 2;
    const int vc   = (t & 3) * 4;
    const short* gV = VT + (bh64 + vrow) * NSEQ + kt0 * 128 + vc * 8;
    short* lVb = Vs + vrow * 128;
    int vch[4];
#pragma unroll
    for (int c = 0; c < 4; ++c) vch[c] = ((vc + c) ^ (vrow & 7)) * 8;

    // read-side swizzled offsets (in shorts)
    const int kofs = (quad ^ r7) * 8;
    int vofs[4];
    {
        const int x4  = r7 & 4;
        const int qr3 = ((quad >> 1) ^ r7) & 3;
#pragma unroll
        for (int s = 0; s < 4; ++s)
            vofs[s] = ((((s << 2) ^ x4) | qr3) * 8) + (quad & 1) * 4;
    }

    // prologue: prefetch tile kt0 into registers
    s16x8 kr[4], vr[4];
#pragma unroll
    for (int c = 0; c < 4; ++c) {
        kr[c] = *(const s16x8*)(gK + c * 8);
        vr[c] = *(const s16x8*)(gV + c * 8);
    }
    const short* gKn = gK + (size_t)128 * EMB;
    const short* gVn = gV + 128;

    for (int it = 0; it < nt; ++it) {
        // write tile from registers (waits vmcnt on the prefetch)
#pragma unroll
        for (int c = 0; c < 4; ++c) {
            *(s16x8*)(lKb + kch[c]) = kr[c];
            *(s16x8*)(lVb + vch[c]) = vr[c];
        }
        __syncthreads();

        // issue prefetch of next tile — overlaps the compute below
        if (it + 1 < nt) {
#pragma unroll
            for (int c = 0; c < 4; ++c) {
                kr[c] = *(const s16x8*)(gKn + c * 8);
                vr[c] = *(const s16x8*)(gVn + c * 8);
            }
            gKn += (size_t)128 * EMB;
            gVn += 128;
        }

        // S^T = K Q^T per key-strip pair; exp2; pack PV B-fragments pf[qs][s]
        s16x8 pf[2][4];
#pragma unroll
        for (int s = 0; s < 4; ++s) {
            const short* kb = Ks + (s * 32 + r) * 64;
            const s16x8 kf00 = *(const s16x8*)(kb + kofs);
            const s16x8 kf01 = *(const s16x8*)(kb + (kofs ^ 32));
            const s16x8 kf10 = *(const s16x8*)(kb + 1024 + kofs);
            const s16x8 kf11 = *(const s16x8*)(kb + 1024 + (kofs ^ 32));
#pragma unroll
            for (int qs = 0; qs < 2; ++qs) {
                __builtin_amdgcn_s_setprio(1);
                f32x4 s0 = __builtin_amdgcn_mfma_f32_16x16x32_bf16(
                    kf01, qf[qs][1], __builtin_amdgcn_mfma_f32_16x16x32_bf16(kf00, qf[qs][0], zf, 0, 0, 0), 0, 0, 0);
                f32x4 s1 = __builtin_amdgcn_mfma_f32_16x16x32_bf16(
                    kf11, qf[qs][1], __builtin_amdgcn_mfma_f32_16x16x32_bf16(kf10, qf[qs][0], zf, 0, 0, 0), 0, 0, 0);
                __builtin_amdgcn_s_setprio(0);
                float p0[4], p1[4];
#pragma unroll
                for (int reg = 0; reg < 4; ++reg) {
                    p0[reg] = fexp2(s0[reg]);
                    p1[reg] = fexp2(s1[reg]);
                    lsum[qs] += p0[reg] + p1[reg];
                }
                uint4 uu = { pkbf(p0[0], p0[1]), pkbf(p0[2], p0[3]),
                             pkbf(p1[0], p1[1]), pkbf(p1[2], p1[3]) };
                __builtin_memcpy(&pf[qs][s], &uu, 16);
            }
        }

        // O^T += V^T P
#pragma unroll
        for (int dt = 0; dt < 4; ++dt) {
            const short* vb = Vs + (dt * 16 + r) * 128;
            s16x8 vfl[4];
#pragma unroll
            for (int s = 0; s < 4; ++s) {
                s16x4 lo = *(const s16x4*)(vb + vofs[s]);
                s16x4 hi = *(const s16x4*)(vb + (vofs[s] ^ 16));
                vfl[s] = __builtin_shufflevector(lo, hi, 0, 1, 2, 3, 4, 5, 6, 7);
            }
            __builtin_amdgcn_s_setprio(1);
#pragma unroll
            for (int qs = 0; qs < 2; ++qs)
#pragma unroll
                for (int s = 0; s < 4; ++s)
                    accO[qs][dt] = __builtin_amdgcn_mfma_f32_16x16x32_bf16(vfl[s], pf[qs][s], accO[qs][dt], 0, 0, 0);
            __builtin_amdgcn_s_setprio(0);
        }
        __syncthreads();
    }

    // row sums + (for PARTIAL) publish them
    float rl[2];
#pragma unroll
    for (int qs = 0; qs < 2; ++qs) {
        float s = lsum[qs];
        s += __shfl_xor(s, 16);
        s += __shfl_xor(s, 32);
        rl[qs] = PARTIAL ? 1.f : 1.f / s;
        if (PARTIAL && lane < 16)
            Lout[ksplit * (NBATCH * NHEAD * NSEQ)
                 + (b * NHEAD + h) * NSEQ + qblk + w * 32 + qs * 16 + r] = s;
    }
    float* Obase = PARTIAL
        ? Outp + (size_t)ksplit * ((size_t)NBATCH * NSEQ * EMB)
        : Outp;

    // Epilogue: O^T (rows=d, cols=q) -> fbuf[q][d] -> coalesced f32x4 stores
#pragma unroll
    for (int qs = 0; qs < 2; ++qs) {
        __syncthreads();
#pragma unroll
        for (int dt = 0; dt < 4; ++dt)
#pragma unroll
            for (int reg = 0; reg < 4; ++reg)
                fbuf[(w * 16 + r) * 68 + dt * 16 + quad * 4 + reg] = accO[qs][dt][reg] * rl[qs];
        __syncthreads();
        const int qi   = t >> 2;
        const int c    = (t & 3) * 16;
        const int wsrc = qi >> 4;
        const int rsrc = qi & 15;
        const float4* fp = (const float4*)&fbuf[(wsrc * 16 + rsrc) * 68 + c];
        float4 o0 = fp[0], o1 = fp[1], o2 = fp[2], o3 = fp[3];
        float* op = Obase + (rowbase + qblk + wsrc * 32 + qs * 16 + rsrc) * EMB + colbase + c;
        ((float4*)op)[0] = o0;
        ((float4*)op)[1] = o1;
        ((float4*)op)[2] = o2;
        ((float4*)op)[3] = o3;
    }
}

// ---------------------------------------------------------------------------
// combine: out = (O0 + O1) / (l0 + l1).  Pure-BW, ~50 MB.
// ---------------------------------------------------------------------------
__global__ __launch_bounds__(256) void comb_kernel(
    const float* __restrict__ O0, const float* __restrict__ O1,
    const float* __restrict__ L0, const float* __restrict__ L1,
    float* __restrict__ Out)
{
    const size_t i = ((size_t)blockIdx.x * 256 + threadIdx.x) * 4;
    const int b = (int)(i >> 21);              // NSEQ*EMB = 2^21
    const int q = (int)((i >> 10) & (NSEQ - 1));
    const int h = (int)((i >> 6) & (NHEAD - 1));
    const int li = (b * NHEAD + h) * NSEQ + q;
    const float rl = 1.f / (L0[li] + L1[li]);
    float4 a = *(const float4*)(O0 + i);
    float4 c = *(const float4*)(O1 + i);
    float4 o = { (a.x + c.x) * rl, (a.y + c.y) * rl, (a.z + c.z) * rl, (a.w + c.w) * rl };
    *(float4*)(Out + i) = o;
}

// ---------------------------------------------------------------------------
// Fallback attention (round-1 structure) for small ws.
// ---------------------------------------------------------------------------
__global__ __launch_bounds__(256) void attn_fb_kernel(
    const short* __restrict__ Qp, const short* __restrict__ Kp,
    const short* __restrict__ Vp, float* __restrict__ Out)
{
    const int qt = blockIdx.x;
    const int h  = blockIdx.y;
    const int b  = blockIdx.z;

    __shared__ __align__(16) short Ks[64][72];
    __shared__ __align__(16) short VsT[64][72];
    __shared__ __align__(16) short Ps[4][16][72];

    const int t    = threadIdx.x;
    const int lane = t & 63;
    const int w    = t >> 6;
    const int r    = lane & 15;
    const int quad = lane >> 4;

    const size_t rowbase = (size_t)b * NSEQ;
    const int colbase    = h * DHEAD;

    const short* Qr = Qp + (rowbase + qt * 64 + w * 16 + r) * EMB + colbase;
    const s16x8 qf0 = *(const s16x8*)(Qr + quad * 8);
    const s16x8 qf1 = *(const s16x8*)(Qr + 32 + quad * 8);

    float mrow[4], lrow[4];
    f32x4 accO[4];
#pragma unroll
    for (int i = 0; i < 4; ++i) {
        mrow[i] = -INFINITY;
        lrow[i] = 0.f;
#pragma unroll
        for (int v = 0; v < 4; ++v) accO[i][v] = 0.f;
    }

    const int srow = t >> 2;
    const int scol = (t & 3) << 4;

    for (int kt = 0; kt < 32; ++kt) {
        const short* Krow = Kp + (rowbase + kt * 64 + srow) * EMB + colbase + scol;
        const short* Vrow = Vp + (rowbase + kt * 64 + srow) * EMB + colbase + scol;
        s16x8 kv0 = *(const s16x8*)Krow;
        s16x8 kv1 = *(const s16x8*)(Krow + 8);
        s16x8 vv0 = *(const s16x8*)Vrow;
        s16x8 vv1 = *(const s16x8*)(Vrow + 8);
        *(s16x8*)&Ks[srow][scol]     = kv0;
        *(s16x8*)&Ks[srow][scol + 8] = kv1;
#pragma unroll
        for (int i = 0; i < 8; ++i) {
            VsT[scol + i][srow]     = vv0[i];
            VsT[scol + 8 + i][srow] = vv1[i];
        }
        __syncthreads();

        f32x4 sacc[4];
#pragma unroll
        for (int j = 0; j < 4; ++j) {
#pragma unroll
            for (int v = 0; v < 4; ++v) sacc[j][v] = 0.f;
            s16x8 kf0 = *(const s16x8*)&Ks[j * 16 + r][quad * 8];
            s16x8 kf1 = *(const s16x8*)&Ks[j * 16 + r][32 + quad * 8];
            sacc[j] = __builtin_amdgcn_mfma_f32_16x16x32_bf16(qf0, kf0, sacc[j], 0, 0, 0);
            sacc[j] = __builtin_amdgcn_mfma_f32_16x16x32_bf16(qf1, kf1, sacc[j], 0, 0, 0);
        }

        float rmax[4];
#pragma unroll
        for (int reg = 0; reg < 4; ++reg) rmax[reg] = -INFINITY;
#pragma unroll
        for (int j = 0; j < 4; ++j)
#pragma unroll
            for (int reg = 0; reg < 4; ++reg)
                rmax[reg] = fmaxf(rmax[reg], sacc[j][reg]);
#pragma unroll
        for (int reg = 0; reg < 4; ++reg) {
#pragma unroll
            for (int mask = 1; mask <= 8; mask <<= 1)
                rmax[reg] = fmaxf(rmax[reg], __shfl_xor(rmax[reg], mask, 64));
        }

        float alpha[4], rsum[4];
#pragma unroll
        for (int reg = 0; reg < 4; ++reg) {
            float mnew = fmaxf(mrow[reg], rmax[reg]);
            alpha[reg] = fexp2(mrow[reg] - mnew);
            mrow[reg]  = mnew;
            rsum[reg]  = 0.f;
        }

#pragma unroll
        for (int j = 0; j < 4; ++j)
#pragma unroll
            for (int reg = 0; reg < 4; ++reg) {
                float p = fexp2(sacc[j][reg] - mrow[reg]);
                rsum[reg] += p;
                Ps[w][quad * 4 + reg][j * 16 + r] = bf16r(p);
            }
#pragma unroll
        for (int reg = 0; reg < 4; ++reg) {
#pragma unroll
            for (int mask = 1; mask <= 8; mask <<= 1)
                rsum[reg] += __shfl_xor(rsum[reg], mask, 64);
            lrow[reg] = lrow[reg] * alpha[reg] + rsum[reg];
        }
#pragma unroll
        for (int j = 0; j < 4; ++j)
#pragma unroll
            for (int reg = 0; reg < 4; ++reg) accO[j][reg] *= alpha[reg];

#pragma unroll
        for (int s = 0; s < 2; ++s) {
            s16x8 pfr = *(const s16x8*)&Ps[w][r][s * 32 + quad * 8];
#pragma unroll
            for (int j = 0; j < 4; ++j) {
                s16x8 vfr = *(const s16x8*)&VsT[j * 16 + r][s * 32 + quad * 8];
                accO[j] = __builtin_amdgcn_mfma_f32_16x16x32_bf16(pfr, vfr, accO[j], 0, 0, 0);
            }
        }
        __syncthreads();
    }

#pragma unroll
    for (int j = 0; j < 4; ++j)
#pragma unroll
        for (int reg = 0; reg < 4; ++reg) {
            const int qrow = qt * 64 + w * 16 + quad * 4 + reg;
            Out[(rowbase + qrow) * EMB + colbase + j * 16 + r] = accO[j][reg] / lrow[reg];
        }
}

extern "C" void kernel_launch(void* const* d_in, const int* in_sizes, int n_in,
                              void* d_out, int out_size, void* d_ws, size_t ws_size,
                              hipStream_t stream) {
    const float* query = (const float*)d_in[0];
    const float* key   = (const float*)d_in[1];
    const float* value = (const float*)d_in[2];
    const float* Wq    = (const float*)d_in[3];
    const float* bq    = (const float*)d_in[4];
    const float* Wk    = (const float*)d_in[5];
    const float* bk    = (const float*)d_in[6];
    const float* Wv    = (const float*)d_in[7];
    const float* bv    = (const float*)d_in[8];
    float* out = (float*)d_out;

    const size_t XBUF = (size_t)NBATCH * NSEQ * EMB;   // 4 Mi elements
    const size_t WBUF = (size_t)EMB * EMB;
    const size_t LBUF = (size_t)NBATCH * NHEAD * NSEQ; // 64 Ki elements

    short* Qb  = (short*)d_ws;
    short* Kb  = Qb + XBUF;
    short* Vb  = Kb + XBUF;
    short* VTb = Vb + XBUF;
    short* Xqb = VTb + XBUF;
    short* Xkb = Xqb + XBUF;
    short* Xvb = Xkb + XBUF;
    short* Wqb = Xvb + XBUF;
    short* Wkb = Wqb + WBUF;
    short* Wvb = Wkb + WBUF;
    float* OP  = (float*)(Wvb + WBUF);   // [2][XBUF] f32 partial O
    float* LP  = OP + 2 * XBUF;          // [2][LBUF] f32 partial sums

    const size_t need_full  = (7 * XBUF + 3 * WBUF) * sizeof(short);
    const size_t need_split = need_full + (2 * XBUF + 2 * LBUF) * sizeof(float);
    const size_t need_attn  = 4 * XBUF * sizeof(short);

    if (ws_size >= need_split) {
        cvt6_kernel<<<dim3(2048, 6), 256, 0, stream>>>(
            query, key, value, Wq, Wk, Wv,
            Xqb, Xkb, Xvb, Wqb, Wkb, Wvb,
            (int)XBUF, (int)XBUF, (int)XBUF, (int)WBUF, (int)WBUF, (int)WBUF);
        proj2_kernel<<<dim3(EMB / 128, (NBATCH * NSEQ) / 128, 3), 256, 0, stream>>>(
            Xqb, Xkb, Xvb, Wqb, Wkb, Wvb, bq, bk, bv, Qb, Kb, VTb);
        attn10_kernel<true><<<dim3(2 * NSEQ / 128, NHEAD, NBATCH), 256, 0, stream>>>(
            Qb, Kb, VTb, OP, LP);
        comb_kernel<<<dim3((unsigned)(XBUF / 1024)), 256, 0, stream>>>(
            OP, OP + XBUF, LP, LP + LBUF, out);
    } else if (ws_size >= need_full) {
        cvt6_kernel<<<dim3(2048, 6), 256, 0, stream>>>(
            query, key, value, Wq, Wk, Wv,
            Xqb, Xkb, Xvb, Wqb, Wkb, Wvb,
            (int)XBUF, (int)XBUF, (int)XBUF, (int)WBUF, (int)WBUF, (int)WBUF);
        proj2_kernel<<<dim3(EMB / 128, (NBATCH * NSEQ) / 128, 3), 256, 0, stream>>>(
            Xqb, Xkb, Xvb, Wqb, Wkb, Wvb, bq, bk, bv, Qb, Kb, VTb);
        attn10_kernel<false><<<dim3(NSEQ / 128, NHEAD, NBATCH), 256, 0, stream>>>(
            Qb, Kb, VTb, out, nullptr);
    } else if (ws_size >= need_attn) {
        proj_kernel<<<dim3(EMB / 128, (NBATCH * NSEQ) / 128, 3), 256, 0, stream>>>(
            query, key, value, Wq, Wk, Wv, bq, bk, bv, Qb, Kb, Vb);
        vtrans_kernel<<<dim3(NSEQ / 64, NHEAD, NBATCH), 256, 0, stream>>>(Vb, VTb);
        attn10_kernel<false><<<dim3(NSEQ / 128, NHEAD, NBATCH), 256, 0, stream>>>(
            Qb, Kb, VTb, out, nullptr);
    } else {
        proj_kernel<<<dim3(EMB / 128, (NBATCH * NSEQ) / 128, 3), 256, 0, stream>>>(
            query, key, value, Wq, Wk, Wv, bq, bk, bv, Qb, Kb, Vb);
        attn_fb_kernel<<<dim3(NSEQ / 64, NHEAD, NBATCH), 256, 0, stream>>>(Qb, Kb, Vb, out);
    }
}

// Round 5
// 210.909 us; speedup vs baseline: 1.4892x; 1.0131x over previous
//
#include <hip/hip_runtime.h>

#define EMB 1024
#define NSEQ 2048
#define NBATCH 2
#define NHEAD 16
#define DHEAD 64
// 0.125 (attn scale) * log2(e), folded into Q at projection time; attn uses exp2
#define QSCALE 0.18033688011112042f

typedef float f32x4 __attribute__((ext_vector_type(4)));
typedef short s16x8 __attribute__((ext_vector_type(8)));
typedef short s16x4 __attribute__((ext_vector_type(4)));

typedef __attribute__((address_space(3))) short lds_short;
typedef __attribute__((address_space(1))) const short glb_short;

__device__ __forceinline__ void gl_lds16(const short* g, short* l) {
    __builtin_amdgcn_global_load_lds((glb_short*)g, (lds_short*)l, 16, 0, 0);
}

__device__ __forceinline__ short bf16r(float f) {
    unsigned u = __float_as_uint(f);
    u += 0x7fffu + ((u >> 16) & 1u);
    return (short)(u >> 16);
}

__device__ __forceinline__ unsigned pkbf(float a, float b) {
#if defined(__has_builtin) && __has_builtin(__builtin_amdgcn_cvt_pk_bf16_f32)
    auto r = __builtin_amdgcn_cvt_pk_bf16_f32(a, b);
    unsigned u;
    __builtin_memcpy(&u, &r, 4);
    return u;
#else
    return ((unsigned)bf16r(a) & 0xffffu) | ((unsigned)bf16r(b) << 16);
#endif
}

__device__ __forceinline__ float fexp2(float x) {
#if defined(__has_builtin) && __has_builtin(__builtin_amdgcn_exp2f)
    return __builtin_amdgcn_exp2f(x);
#else
    return exp2f(x);
#endif
}

// ---------------------------------------------------------------------------
// fp32 -> bf16 conversion pass (memory-bound). grid.y = segment 0..5.
// ---------------------------------------------------------------------------
__global__ __launch_bounds__(256) void cvt6_kernel(
    const float* __restrict__ s0, const float* __restrict__ s1, const float* __restrict__ s2,
    const float* __restrict__ s3, const float* __restrict__ s4, const float* __restrict__ s5,
    short* __restrict__ d0, short* __restrict__ d1, short* __restrict__ d2,
    short* __restrict__ d3, short* __restrict__ d4, short* __restrict__ d5,
    int n0, int n1, int n2, int n3, int n4, int n5)
{
    const int seg = blockIdx.y;
    const float* s = (seg == 0) ? s0 : (seg == 1) ? s1 : (seg == 2) ? s2
                   : (seg == 3) ? s3 : (seg == 4) ? s4 : s5;
    short* d = (seg == 0) ? d0 : (seg == 1) ? d1 : (seg == 2) ? d2
             : (seg == 3) ? d3 : (seg == 4) ? d4 : d5;
    const int n = (seg == 0) ? n0 : (seg == 1) ? n1 : (seg == 2) ? n2
                : (seg == 3) ? n3 : (seg == 4) ? n4 : n5;

    const int i = (blockIdx.x * 256 + threadIdx.x) * 8;
    if (i >= n) return;
    float4 a = *(const float4*)(s + i);
    float4 b = *(const float4*)(s + i + 4);
    uint4 u = { pkbf(a.x, a.y), pkbf(a.z, a.w), pkbf(b.x, b.y), pkbf(b.z, b.w) };
    *(uint4*)(d + i) = u;
}

// ---------------------------------------------------------------------------
// proj2: bf16 NT GEMM. 128x128 tile, BK=64, 4 waves x 64x64 quadrant.
// global_load_lds width=16 into UNPADDED LDS, XOR chunk swizzle (^ row&7).
// z==2 (V projection) writes the TRANSPOSED VT layout directly (kills vtrans).
// ---------------------------------------------------------------------------
__global__ __launch_bounds__(256, 3) void proj2_kernel(
    const short* __restrict__ Xq, const short* __restrict__ Xk, const short* __restrict__ Xv,
    const short* __restrict__ Wq, const short* __restrict__ Wk, const short* __restrict__ Wv,
    const float* __restrict__ bq, const float* __restrict__ bk, const float* __restrict__ bv,
    short* __restrict__ Oq, short* __restrict__ Ok, short* __restrict__ Ov)
{
    const int z = blockIdx.z;
    const short* X    = (z == 0) ? Xq : (z == 1) ? Xk : Xv;
    const short* W    = (z == 0) ? Wq : (z == 1) ? Wk : Wv;
    const float* bias = (z == 0) ? bq : (z == 1) ? bk : bv;
    short* Out        = (z == 0) ? Oq : (z == 1) ? Ok : Ov;
    const float osc   = (z == 0) ? QSCALE : 1.0f;

    const int n0 = blockIdx.x * 128;
    const int m0 = blockIdx.y * 128;

    __shared__ __align__(16) short As[128 * 64];
    __shared__ __align__(16) short Bs[128 * 64];

    const int t    = threadIdx.x;
    const int lane = t & 63;
    const int wave = t >> 6;
    const int r    = lane & 15;
    const int quad = lane >> 4;
    const int wm   = (wave >> 1) * 64;
    const int wn   = (wave & 1) * 64;

    const int p0    = wave * 256 + lane;
    const int row0  = p0 >> 3;
    const int lc0   = (p0 & 7) ^ (row0 & 7);
    const short* gA = X + (size_t)(m0 + row0) * EMB + lc0 * 8;
    const short* gB = W + (size_t)(n0 + row0) * EMB + lc0 * 8;
    short* lA = As + p0 * 8;
    short* lB = Bs + p0 * 8;

    f32x4 acc[4][4];
#pragma unroll
    for (int i = 0; i < 4; ++i)
#pragma unroll
        for (int j = 0; j < 4; ++j)
#pragma unroll
            for (int v = 0; v < 4; ++v) acc[i][j][v] = 0.f;

    for (int k0 = 0; k0 < EMB; k0 += 64) {
#pragma unroll
        for (int i = 0; i < 4; ++i) {
            gl_lds16(gA + k0 + (size_t)8 * i * EMB, lA + i * 512);
            gl_lds16(gB + k0 + (size_t)8 * i * EMB, lB + i * 512);
        }
        __syncthreads();

#pragma unroll
        for (int ks = 0; ks < 2; ++ks) {
            const int fc = ((ks * 4 + quad) ^ (r & 7)) * 8;
            s16x8 af[4], bf[4];
#pragma unroll
            for (int i = 0; i < 4; ++i) af[i] = *(const s16x8*)&As[(wm + i * 16 + r) * 64 + fc];
#pragma unroll
            for (int j = 0; j < 4; ++j) bf[j] = *(const s16x8*)&Bs[(wn + j * 16 + r) * 64 + fc];
#pragma unroll
            for (int i = 0; i < 4; ++i)
#pragma unroll
                for (int j = 0; j < 4; ++j)
                    acc[i][j] = __builtin_amdgcn_mfma_f32_16x16x32_bf16(af[i], bf[j], acc[i][j], 0, 0, 0);
        }
        __syncthreads();
    }

    if (z != 2) {
#pragma unroll
        for (int j = 0; j < 4; ++j) {
            const int gn = n0 + wn + j * 16 + r;
            const float bb = bias[gn];
#pragma unroll
            for (int i = 0; i < 4; ++i)
#pragma unroll
                for (int reg = 0; reg < 4; ++reg) {
                    const int gm = m0 + wm + i * 16 + quad * 4 + reg;
                    Out[(size_t)gm * EMB + gn] = bf16r((acc[i][j][reg] + bb) * osc);
                }
        }
    } else {
        // V: write VT[(b*16+h)*64+d][token] directly.  gn -> (h,d), gm -> (b,token).
#pragma unroll
        for (int j = 0; j < 4; ++j) {
            const int gn = n0 + wn + j * 16 + r;
            const float bb = bias[gn];
            const int hh = gn >> 6;
            const int dd = gn & 63;
#pragma unroll
            for (int i = 0; i < 4; ++i) {
                const int gm = m0 + wm + i * 16 + quad * 4;
                const int bi = gm >> 11;
                const int nn = gm & 2047;
                s16x4 pk;
#pragma unroll
                for (int reg = 0; reg < 4; ++reg) pk[reg] = bf16r(acc[i][j][reg] + bb);
                *(s16x4*)(Out + ((size_t)(bi * NHEAD + hh) * DHEAD + dd) * NSEQ + nn) = pk;
            }
        }
    }
}

// ---------------------------------------------------------------------------
// Fallback projection (fp32 inputs, convert during staging). Row-major outputs.
// ---------------------------------------------------------------------------
__global__ __launch_bounds__(256) void proj_kernel(
    const float* __restrict__ Xq, const float* __restrict__ Xk, const float* __restrict__ Xv,
    const float* __restrict__ Wq, const float* __restrict__ Wk, const float* __restrict__ Wv,
    const float* __restrict__ bq, const float* __restrict__ bk, const float* __restrict__ bv,
    short* __restrict__ Oq, short* __restrict__ Ok, short* __restrict__ Ov)
{
    const int z = blockIdx.z;
    const float* X    = (z == 0) ? Xq : (z == 1) ? Xk : Xv;
    const float* W    = (z == 0) ? Wq : (z == 1) ? Wk : Wv;
    const float* bias = (z == 0) ? bq : (z == 1) ? bk : bv;
    short* Out        = (z == 0) ? Oq : (z == 1) ? Ok : Ov;
    const float osc   = (z == 0) ? QSCALE : 1.0f;

    const int n0 = blockIdx.x * 128;
    const int m0 = blockIdx.y * 128;

    __shared__ __align__(16) short As[128][40];
    __shared__ __align__(16) short Bs[128][40];

    const int t    = threadIdx.x;
    const int lane = t & 63;
    const int wave = t >> 6;
    const int r    = lane & 15;
    const int quad = lane >> 4;
    const int wm   = (wave >> 1) * 64;
    const int wn   = (wave & 1) * 64;

    const int srow = t >> 1;
    const int scol = (t & 1) << 4;

    f32x4 acc[4][4];
#pragma unroll
    for (int i = 0; i < 4; ++i)
#pragma unroll
        for (int j = 0; j < 4; ++j)
#pragma unroll
            for (int v = 0; v < 4; ++v) acc[i][j][v] = 0.f;

    for (int k0 = 0; k0 < EMB; k0 += 32) {
        const float4* xp = (const float4*)(X + (size_t)(m0 + srow) * EMB + k0 + scol);
        const float4* wp = (const float4*)(W + (size_t)(n0 + srow) * EMB + k0 + scol);
        float4 x0 = xp[0], x1 = xp[1], x2 = xp[2], x3 = xp[3];
        float4 w0 = wp[0], w1 = wp[1], w2 = wp[2], w3 = wp[3];
        uint4 a0 = { pkbf(x0.x, x0.y), pkbf(x0.z, x0.w), pkbf(x1.x, x1.y), pkbf(x1.z, x1.w) };
        uint4 a1 = { pkbf(x2.x, x2.y), pkbf(x2.z, x2.w), pkbf(x3.x, x3.y), pkbf(x3.z, x3.w) };
        uint4 b0 = { pkbf(w0.x, w0.y), pkbf(w0.z, w0.w), pkbf(w1.x, w1.y), pkbf(w1.z, w1.w) };
        uint4 b1 = { pkbf(w2.x, w2.y), pkbf(w2.z, w2.w), pkbf(w3.x, w3.y), pkbf(w3.z, w3.w) };
        *(uint4*)&As[srow][scol]     = a0;
        *(uint4*)&As[srow][scol + 8] = a1;
        *(uint4*)&Bs[srow][scol]     = b0;
        *(uint4*)&Bs[srow][scol + 8] = b1;
        __syncthreads();

        s16x8 af[4], bf[4];
#pragma unroll
        for (int i = 0; i < 4; ++i) af[i] = *(const s16x8*)&As[wm + i * 16 + r][quad * 8];
#pragma unroll
        for (int j = 0; j < 4; ++j) bf[j] = *(const s16x8*)&Bs[wn + j * 16 + r][quad * 8];
#pragma unroll
        for (int i = 0; i < 4; ++i)
#pragma unroll
            for (int j = 0; j < 4; ++j)
                acc[i][j] = __builtin_amdgcn_mfma_f32_16x16x32_bf16(af[i], bf[j], acc[i][j], 0, 0, 0);
        __syncthreads();
    }

#pragma unroll
    for (int j = 0; j < 4; ++j) {
        const int gn = n0 + wn + j * 16 + r;
        const float bb = bias[gn];
#pragma unroll
        for (int i = 0; i < 4; ++i)
#pragma unroll
            for (int reg = 0; reg < 4; ++reg) {
                const int gm = m0 + wm + i * 16 + quad * 4 + reg;
                Out[(size_t)gm * EMB + gn] = bf16r((acc[i][j][reg] + bb) * osc);
            }
    }
}

// ---------------------------------------------------------------------------
// V transpose (fallback path only): V [b*2048+n][h*64+d] -> VT [(b*16+h)*64+d][n]
// ---------------------------------------------------------------------------
__global__ __launch_bounds__(256) void vtrans_kernel(
    const short* __restrict__ Vp, short* __restrict__ VT)
{
    const int n0 = blockIdx.x * 64;
    const int h  = blockIdx.y;
    const int b  = blockIdx.z;
    __shared__ __align__(16) short L[64][72];

    const int t  = threadIdx.x;
    const int rr = t >> 2;
    const int cc = (t & 3) * 16;

    const short* src = Vp + (size_t)(b * NSEQ + n0 + rr) * EMB + h * DHEAD + cc;
    s16x8 a = *(const s16x8*)src;
    s16x8 c = *(const s16x8*)(src + 8);
    *(s16x8*)&L[rr][cc]     = a;
    *(s16x8*)&L[rr][cc + 8] = c;
    __syncthreads();

    const int d  = t >> 2;
    const int c4 = (t & 3) * 16;
    short vals[16];
#pragma unroll
    for (int i = 0; i < 16; ++i) vals[i] = L[c4 + i][d];
    short* dst = VT + ((size_t)(b * NHEAD + h) * DHEAD + d) * NSEQ + n0 + c4;
    *(s16x8*)dst       = *(s16x8*)&vals[0];
    *(s16x8*)(dst + 8) = *(s16x8*)&vals[8];
}

// ---------------------------------------------------------------------------
// attn11: attn10 compute (verified) with global_load_lds staging.
// Staging uses PRE-SWIZZLED GLOBAL source + LINEAR LDS dest (m173): LDS slot s
// of row holds global chunk s^(row&7) — byte-identical layout to attn10, so
// all compute-side read formulas are unchanged.  Removing the 32-reg register
// prefetch + staging addressing drops peak state to ~140 regs, so
// __launch_bounds__(256,3) (170-reg unified budget) compiles WITHOUT spill
// -> 3 waves/SIMD -> 3 blocks/CU on the 1024-block split grid.
// History: (256,4)=128 cap -> catastrophic spill (R2/R3); (256,2) -> lazy
// ~180+ unified alloc -> stuck at 2 blocks/CU, no speedup (R4).
// ---------------------------------------------------------------------------
template<bool PARTIAL>
__global__ __launch_bounds__(256, 3) void attn11_kernel(
    const short* __restrict__ Qp, const short* __restrict__ Kp,
    const short* __restrict__ VT, float* __restrict__ Outp,
    float* __restrict__ Lout)
{
    const int ksplit = PARTIAL ? (blockIdx.x & 1) : 0;
    const int qblk   = (PARTIAL ? (blockIdx.x >> 1) : blockIdx.x) * 128;
    const int h      = blockIdx.y;
    const int b      = blockIdx.z;
    const int nt     = PARTIAL ? 8 : 16;
    const int kt0    = PARTIAL ? ksplit * 8 : 0;

    __shared__ __align__(16) char smem[32768];
    short* Ks   = (short*)smem;               // [128][64] key x d, chunk-swizzled
    short* Vs   = (short*)smem + 128 * 64;    // [64][128] d x key, chunk-swizzled
    float* fbuf = (float*)smem;               // [64][68] floats (union, epilogue)

    const int t    = threadIdx.x;
    const int lane = t & 63;
    const int w    = t >> 6;         // q-strip: rows qblk + w*32 + qs*16 + r
    const int r    = lane & 15;
    const int quad = lane >> 4;
    const int r7   = r & 7;

    const size_t rowbase = (size_t)b * NSEQ;
    const int    colbase = h * DHEAD;
    const size_t bh64    = (size_t)(b * NHEAD + h) * DHEAD;

    // Q B-fragments
    s16x8 qf[2][2];
#pragma unroll
    for (int qs = 0; qs < 2; ++qs)
#pragma unroll
        for (int ks = 0; ks < 2; ++ks)
            qf[qs][ks] = *(const s16x8*)(Qp + (rowbase + qblk + w * 32 + qs * 16 + r) * EMB
                                          + colbase + ks * 32 + quad * 8);

    f32x4 accO[2][4];
#pragma unroll
    for (int qs = 0; qs < 2; ++qs)
#pragma unroll
        for (int dt = 0; dt < 4; ++dt)
#pragma unroll
            for (int v = 0; v < 4; ++v) accO[qs][dt][v] = 0.f;
    float lsum[2] = {0.f, 0.f};
    const f32x4 zf = {0.f, 0.f, 0.f, 0.f};

    // --- gl_lds staging addresses -----------------------------------------
    // K: LDS chunk p = i*256+t -> row = p>>3 (= t>>3 + 32i), slot = p&7 (= t&7).
    //    Slot s holds global chunk s^(row&7); row&7 is i-invariant (32 ≡ 0 mod 8).
    // V: LDS chunk p = i*256+t -> row = p>>4 (= t>>4 + 16i), slot = p&15.
    const int  krow0 = t >> 3;
    const int  kgc   = ((t & 7) ^ (krow0 & 7)) * 8;
    const int  vrow0 = t >> 4;
    const int  vgc   = ((t & 15) ^ (vrow0 & 7)) * 8;
    const short* gK[4];
    const short* gV[4];
    {
        const short* kb0 = Kp + (rowbase + kt0 * 128 + krow0) * EMB + colbase + kgc;
        const short* vb0 = VT + (bh64 + vrow0) * NSEQ + kt0 * 128 + vgc;
#pragma unroll
        for (int i = 0; i < 4; ++i) {
            gK[i] = kb0 + (size_t)i * 32 * EMB;
            gV[i] = vb0 + (size_t)i * 16 * NSEQ;
        }
    }
    short* lK[4];
    short* lV[4];
#pragma unroll
    for (int i = 0; i < 4; ++i) {
        lK[i] = Ks + (i * 256 + t) * 8;
        lV[i] = Vs + (i * 256 + t) * 8;
    }

    // read-side swizzled offsets (in shorts)
    const int kofs = (quad ^ r7) * 8;
    int vofs[4];
    {
        const int x4  = r7 & 4;
        const int qr3 = ((quad >> 1) ^ r7) & 3;
#pragma unroll
        for (int s = 0; s < 4; ++s)
            vofs[s] = ((((s << 2) ^ x4) | qr3) * 8) + (quad & 1) * 4;
    }

    for (int it = 0; it < nt; ++it) {
        // async global -> LDS for tile it (prev barrier protects the buffer)
#pragma unroll
        for (int i = 0; i < 4; ++i) {
            gl_lds16(gK[i], lK[i]);
            gl_lds16(gV[i], lV[i]);
        }
#pragma unroll
        for (int i = 0; i < 4; ++i) {
            gK[i] += (size_t)128 * EMB;
            gV[i] += 128;
        }
        __syncthreads();   // drains vmcnt(0): tile data resident in LDS

        // S^T = K Q^T per key-strip pair; exp2; pack PV B-fragments pf[qs][s]
        s16x8 pf[2][4];
#pragma unroll
        for (int s = 0; s < 4; ++s) {
            const short* kb = Ks + (s * 32 + r) * 64;
            const s16x8 kf00 = *(const s16x8*)(kb + kofs);
            const s16x8 kf01 = *(const s16x8*)(kb + (kofs ^ 32));
            const s16x8 kf10 = *(const s16x8*)(kb + 1024 + kofs);
            const s16x8 kf11 = *(const s16x8*)(kb + 1024 + (kofs ^ 32));
#pragma unroll
            for (int qs = 0; qs < 2; ++qs) {
                __builtin_amdgcn_s_setprio(1);
                f32x4 s0 = __builtin_amdgcn_mfma_f32_16x16x32_bf16(
                    kf01, qf[qs][1], __builtin_amdgcn_mfma_f32_16x16x32_bf16(kf00, qf[qs][0], zf, 0, 0, 0), 0, 0, 0);
                f32x4 s1 = __builtin_amdgcn_mfma_f32_16x16x32_bf16(
                    kf11, qf[qs][1], __builtin_amdgcn_mfma_f32_16x16x32_bf16(kf10, qf[qs][0], zf, 0, 0, 0), 0, 0, 0);
                __builtin_amdgcn_s_setprio(0);
                float p0[4], p1[4];
#pragma unroll
                for (int reg = 0; reg < 4; ++reg) {
                    p0[reg] = fexp2(s0[reg]);
                    p1[reg] = fexp2(s1[reg]);
                    lsum[qs] += p0[reg] + p1[reg];
                }
                uint4 uu = { pkbf(p0[0], p0[1]), pkbf(p0[2], p0[3]),
                             pkbf(p1[0], p1[1]), pkbf(p1[2], p1[3]) };
                __builtin_memcpy(&pf[qs][s], &uu, 16);
            }
        }

        // O^T += V^T P
#pragma unroll
        for (int dt = 0; dt < 4; ++dt) {
            const short* vb = Vs + (dt * 16 + r) * 128;
            s16x8 vfl[4];
#pragma unroll
            for (int s = 0; s < 4; ++s) {
                s16x4 lo = *(const s16x4*)(vb + vofs[s]);
                s16x4 hi = *(const s16x4*)(vb + (vofs[s] ^ 16));
                vfl[s] = __builtin_shufflevector(lo, hi, 0, 1, 2, 3, 4, 5, 6, 7);
            }
            __builtin_amdgcn_s_setprio(1);
#pragma unroll
            for (int qs = 0; qs < 2; ++qs)
#pragma unroll
                for (int s = 0; s < 4; ++s)
                    accO[qs][dt] = __builtin_amdgcn_mfma_f32_16x16x32_bf16(vfl[s], pf[qs][s], accO[qs][dt], 0, 0, 0);
            __builtin_amdgcn_s_setprio(0);
        }
        __syncthreads();   // all reads done before next tile's gl_lds writes
    }

    // row sums + (for PARTIAL) publish them
    float rl[2];
#pragma unroll
    for (int qs = 0; qs < 2; ++qs) {
        float s = lsum[qs];
        s += __shfl_xor(s, 16);
        s += __shfl_xor(s, 32);
        rl[qs] = PARTIAL ? 1.f : 1.f / s;
        if (PARTIAL && lane < 16)
            Lout[ksplit * (NBATCH * NHEAD * NSEQ)
                 + (b * NHEAD + h) * NSEQ + qblk + w * 32 + qs * 16 + r] = s;
    }
    float* Obase = PARTIAL
        ? Outp + (size_t)ksplit * ((size_t)NBATCH * NSEQ * EMB)
        : Outp;

    // Epilogue: O^T (rows=d, cols=q) -> fbuf[q][d] -> coalesced f32x4 stores
#pragma unroll
    for (int qs = 0; qs < 2; ++qs) {
        __syncthreads();
#pragma unroll
        for (int dt = 0; dt < 4; ++dt)
#pragma unroll
            for (int reg = 0; reg < 4; ++reg)
                fbuf[(w * 16 + r) * 68 + dt * 16 + quad * 4 + reg] = accO[qs][dt][reg] * rl[qs];
        __syncthreads();
        const int qi   = t >> 2;
        const int c    = (t & 3) * 16;
        const int wsrc = qi >> 4;
        const int rsrc = qi & 15;
        const float4* fp = (const float4*)&fbuf[(wsrc * 16 + rsrc) * 68 + c];
        float4 o0 = fp[0], o1 = fp[1], o2 = fp[2], o3 = fp[3];
        float* op = Obase + (rowbase + qblk + wsrc * 32 + qs * 16 + rsrc) * EMB + colbase + c;
        ((float4*)op)[0] = o0;
        ((float4*)op)[1] = o1;
        ((float4*)op)[2] = o2;
        ((float4*)op)[3] = o3;
    }
}

// ---------------------------------------------------------------------------
// combine: out = (O0 + O1) / (l0 + l1).  Pure-BW, ~50 MB.
// ---------------------------------------------------------------------------
__global__ __launch_bounds__(256) void comb_kernel(
    const float* __restrict__ O0, const float* __restrict__ O1,
    const float* __restrict__ L0, const float* __restrict__ L1,
    float* __restrict__ Out)
{
    const size_t i = ((size_t)blockIdx.x * 256 + threadIdx.x) * 4;
    const int b = (int)(i >> 21);              // NSEQ*EMB = 2^21
    const int q = (int)((i >> 10) & (NSEQ - 1));
    const int h = (int)((i >> 6) & (NHEAD - 1));
    const int li = (b * NHEAD + h) * NSEQ + q;
    const float rl = 1.f / (L0[li] + L1[li]);
    float4 a = *(const float4*)(O0 + i);
    float4 c = *(const float4*)(O1 + i);
    float4 o = { (a.x + c.x) * rl, (a.y + c.y) * rl, (a.z + c.z) * rl, (a.w + c.w) * rl };
    *(float4*)(Out + i) = o;
}

// ---------------------------------------------------------------------------
// Fallback attention (round-1 structure) for small ws.
// ---------------------------------------------------------------------------
__global__ __launch_bounds__(256) void attn_fb_kernel(
    const short* __restrict__ Qp, const short* __restrict__ Kp,
    const short* __restrict__ Vp, float* __restrict__ Out)
{
    const int qt = blockIdx.x;
    const int h  = blockIdx.y;
    const int b  = blockIdx.z;

    __shared__ __align__(16) short Ks[64][72];
    __shared__ __align__(16) short VsT[64][72];
    __shared__ __align__(16) short Ps[4][16][72];

    const int t    = threadIdx.x;
    const int lane = t & 63;
    const int w    = t >> 6;
    const int r    = lane & 15;
    const int quad = lane >> 4;

    const size_t rowbase = (size_t)b * NSEQ;
    const int colbase    = h * DHEAD;

    const short* Qr = Qp + (rowbase + qt * 64 + w * 16 + r) * EMB + colbase;
    const s16x8 qf0 = *(const s16x8*)(Qr + quad * 8);
    const s16x8 qf1 = *(const s16x8*)(Qr + 32 + quad * 8);

    float mrow[4], lrow[4];
    f32x4 accO[4];
#pragma unroll
    for (int i = 0; i < 4; ++i) {
        mrow[i] = -INFINITY;
        lrow[i] = 0.f;
#pragma unroll
        for (int v = 0; v < 4; ++v) accO[i][v] = 0.f;
    }

    const int srow = t >> 2;
    const int scol = (t & 3) << 4;

    for (int kt = 0; kt < 32; ++kt) {
        const short* Krow = Kp + (rowbase + kt * 64 + srow) * EMB + colbase + scol;
        const short* Vrow = Vp + (rowbase + kt * 64 + srow) * EMB + colbase + scol;
        s16x8 kv0 = *(const s16x8*)Krow;
        s16x8 kv1 = *(const s16x8*)(Krow + 8);
        s16x8 vv0 = *(const s16x8*)Vrow;
        s16x8 vv1 = *(const s16x8*)(Vrow + 8);
        *(s16x8*)&Ks[srow][scol]     = kv0;
        *(s16x8*)&Ks[srow][scol + 8] = kv1;
#pragma unroll
        for (int i = 0; i < 8; ++i) {
            VsT[scol + i][srow]     = vv0[i];
            VsT[scol + 8 + i][srow] = vv1[i];
        }
        __syncthreads();

        f32x4 sacc[4];
#pragma unroll
        for (int j = 0; j < 4; ++j) {
#pragma unroll
            for (int v = 0; v < 4; ++v) sacc[j][v] = 0.f;
            s16x8 kf0 = *(const s16x8*)&Ks[j * 16 + r][quad * 8];
            s16x8 kf1 = *(const s16x8*)&Ks[j * 16 + r][32 + quad * 8];
            sacc[j] = __builtin_amdgcn_mfma_f32_16x16x32_bf16(qf0, kf0, sacc[j], 0, 0, 0);
            sacc[j] = __builtin_amdgcn_mfma_f32_16x16x32_bf16(qf1, kf1, sacc[j], 0, 0, 0);
        }

        float rmax[4];
#pragma unroll
        for (int reg = 0; reg < 4; ++reg) rmax[reg] = -INFINITY;
#pragma unroll
        for (int j = 0; j < 4; ++j)
#pragma unroll
            for (int reg = 0; reg < 4; ++reg)
                rmax[reg] = fmaxf(rmax[reg], sacc[j][reg]);
#pragma unroll
        for (int reg = 0; reg < 4; ++reg) {
#pragma unroll
            for (int mask = 1; mask <= 8; mask <<= 1)
                rmax[reg] = fmaxf(rmax[reg], __shfl_xor(rmax[reg], mask, 64));
        }

        float alpha[4], rsum[4];
#pragma unroll
        for (int reg = 0; reg < 4; ++reg) {
            float mnew = fmaxf(mrow[reg], rmax[reg]);
            alpha[reg] = fexp2(mrow[reg] - mnew);
            mrow[reg]  = mnew;
            rsum[reg]  = 0.f;
        }

#pragma unroll
        for (int j = 0; j < 4; ++j)
#pragma unroll
            for (int reg = 0; reg < 4; ++reg) {
                float p = fexp2(sacc[j][reg] - mrow[reg]);
                rsum[reg] += p;
                Ps[w][quad * 4 + reg][j * 16 + r] = bf16r(p);
            }
#pragma unroll
        for (int reg = 0; reg < 4; ++reg) {
#pragma unroll
            for (int mask = 1; mask <= 8; mask <<= 1)
                rsum[reg] += __shfl_xor(rsum[reg], mask, 64);
            lrow[reg] = lrow[reg] * alpha[reg] + rsum[reg];
        }
#pragma unroll
        for (int j = 0; j < 4; ++j)
#pragma unroll
            for (int reg = 0; reg < 4; ++reg) accO[j][reg] *= alpha[reg];

#pragma unroll
        for (int s = 0; s < 2; ++s) {
            s16x8 pfr = *(const s16x8*)&Ps[w][r][s * 32 + quad * 8];
#pragma unroll
            for (int j = 0; j < 4; ++j) {
                s16x8 vfr = *(const s16x8*)&VsT[j * 16 + r][s * 32 + quad * 8];
                accO[j] = __builtin_amdgcn_mfma_f32_16x16x32_bf16(pfr, vfr, accO[j], 0, 0, 0);
            }
        }
        __syncthreads();
    }

#pragma unroll
    for (int j = 0; j < 4; ++j)
#pragma unroll
        for (int reg = 0; reg < 4; ++reg) {
            const int qrow = qt * 64 + w * 16 + quad * 4 + reg;
            Out[(rowbase + qrow) * EMB + colbase + j * 16 + r] = accO[j][reg] / lrow[reg];
        }
}

extern "C" void kernel_launch(void* const* d_in, const int* in_sizes, int n_in,
                              void* d_out, int out_size, void* d_ws, size_t ws_size,
                              hipStream_t stream) {
    const float* query = (const float*)d_in[0];
    const float* key   = (const float*)d_in[1];
    const float* value = (const float*)d_in[2];
    const float* Wq    = (const float*)d_in[3];
    const float* bq    = (const float*)d_in[4];
    const float* Wk    = (const float*)d_in[5];
    const float* bk    = (const float*)d_in[6];
    const float* Wv    = (const float*)d_in[7];
    const float* bv    = (const float*)d_in[8];
    float* out = (float*)d_out;

    const size_t XBUF = (size_t)NBATCH * NSEQ * EMB;   // 4 Mi elements
    const size_t WBUF = (size_t)EMB * EMB;
    const size_t LBUF = (size_t)NBATCH * NHEAD * NSEQ; // 64 Ki elements

    short* Qb  = (short*)d_ws;
    short* Kb  = Qb + XBUF;
    short* Vb  = Kb + XBUF;
    short* VTb = Vb + XBUF;
    short* Xqb = VTb + XBUF;
    short* Xkb = Xqb + XBUF;
    short* Xvb = Xkb + XBUF;
    short* Wqb = Xvb + XBUF;
    short* Wkb = Wqb + WBUF;
    short* Wvb = Wkb + WBUF;
    float* OP  = (float*)(Wvb + WBUF);   // [2][XBUF] f32 partial O
    float* LP  = OP + 2 * XBUF;          // [2][LBUF] f32 partial sums

    const size_t need_full  = (7 * XBUF + 3 * WBUF) * sizeof(short);
    const size_t need_split = need_full + (2 * XBUF + 2 * LBUF) * sizeof(float);
    const size_t need_attn  = 4 * XBUF * sizeof(short);

    if (ws_size >= need_split) {
        cvt6_kernel<<<dim3(2048, 6), 256, 0, stream>>>(
            query, key, value, Wq, Wk, Wv,
            Xqb, Xkb, Xvb, Wqb, Wkb, Wvb,
            (int)XBUF, (int)XBUF, (int)XBUF, (int)WBUF, (int)WBUF, (int)WBUF);
        proj2_kernel<<<dim3(EMB / 128, (NBATCH * NSEQ) / 128, 3), 256, 0, stream>>>(
            Xqb, Xkb, Xvb, Wqb, Wkb, Wvb, bq, bk, bv, Qb, Kb, VTb);
        attn11_kernel<true><<<dim3(2 * NSEQ / 128, NHEAD, NBATCH), 256, 0, stream>>>(
            Qb, Kb, VTb, OP, LP);
        comb_kernel<<<dim3((unsigned)(XBUF / 1024)), 256, 0, stream>>>(
            OP, OP + XBUF, LP, LP + LBUF, out);
    } else if (ws_size >= need_full) {
        cvt6_kernel<<<dim3(2048, 6), 256, 0, stream>>>(
            query, key, value, Wq, Wk, Wv,
            Xqb, Xkb, Xvb, Wqb, Wkb, Wvb,
            (int)XBUF, (int)XBUF, (int)XBUF, (int)WBUF, (int)WBUF, (int)WBUF);
        proj2_kernel<<<dim3(EMB / 128, (NBATCH * NSEQ) / 128, 3), 256, 0, stream>>>(
            Xqb, Xkb, Xvb, Wqb, Wkb, Wvb, bq, bk, bv, Qb, Kb, VTb);
        attn11_kernel<false><<<dim3(NSEQ / 128, NHEAD, NBATCH), 256, 0, stream>>>(
            Qb, Kb, VTb, out, nullptr);
    } else if (ws_size >= need_attn) {
        proj_kernel<<<dim3(EMB / 128, (NBATCH * NSEQ) / 128, 3), 256, 0, stream>>>(
            query, key, value, Wq, Wk, Wv, bq, bk, bv, Qb, Kb, Vb);
        vtrans_kernel<<<dim3(NSEQ / 64, NHEAD, NBATCH), 256, 0, stream>>>(Vb, VTb);
        attn11_kernel<false><<<dim3(NSEQ / 128, NHEAD, NBATCH), 256, 0, stream>>>(
            Qb, Kb, VTb, out, nullptr);
    } else {
        proj_kernel<<<dim3(EMB / 128, (NBATCH * NSEQ) / 128, 3), 256, 0, stream>>>(
            query, key, value, Wq, Wk, Wv, bq, bk, bv, Qb, Kb, Vb);
        attn_fb_kernel<<<dim3(NSEQ / 64, NHEAD, NBATCH), 256, 0, stream>>>(Qb, Kb, Vb, out);
    }
}

// Round 6
// 199.584 us; speedup vs baseline: 1.5737x; 1.0567x over previous
//
#include <hip/hip_runtime.h>

#define EMB 1024
#define NSEQ 2048
#define NBATCH 2
#define NHEAD 16
#define DHEAD 64
// 0.125 (attn scale) * log2(e), folded into Q at projection time; attn uses exp2
#define QSCALE 0.18033688011112042f

typedef float f32x4 __attribute__((ext_vector_type(4)));
typedef short s16x8 __attribute__((ext_vector_type(8)));
typedef short s16x4 __attribute__((ext_vector_type(4)));

typedef __attribute__((address_space(3))) short lds_short;
typedef __attribute__((address_space(1))) const short glb_short;

__device__ __forceinline__ void gl_lds16(const short* g, short* l) {
    __builtin_amdgcn_global_load_lds((glb_short*)g, (lds_short*)l, 16, 0, 0);
}

__device__ __forceinline__ short bf16r(float f) {
    unsigned u = __float_as_uint(f);
    u += 0x7fffu + ((u >> 16) & 1u);
    return (short)(u >> 16);
}

__device__ __forceinline__ unsigned pkbf(float a, float b) {
#if defined(__has_builtin) && __has_builtin(__builtin_amdgcn_cvt_pk_bf16_f32)
    auto r = __builtin_amdgcn_cvt_pk_bf16_f32(a, b);
    unsigned u;
    __builtin_memcpy(&u, &r, 4);
    return u;
#else
    return ((unsigned)bf16r(a) & 0xffffu) | ((unsigned)bf16r(b) << 16);
#endif
}

__device__ __forceinline__ float fexp2(float x) {
#if defined(__has_builtin) && __has_builtin(__builtin_amdgcn_exp2f)
    return __builtin_amdgcn_exp2f(x);
#else
    return exp2f(x);
#endif
}

// ---------------------------------------------------------------------------
// fp32 -> bf16 conversion pass (memory-bound). grid.y = segment 0..5.
// ---------------------------------------------------------------------------
__global__ __launch_bounds__(256) void cvt6_kernel(
    const float* __restrict__ s0, const float* __restrict__ s1, const float* __restrict__ s2,
    const float* __restrict__ s3, const float* __restrict__ s4, const float* __restrict__ s5,
    short* __restrict__ d0, short* __restrict__ d1, short* __restrict__ d2,
    short* __restrict__ d3, short* __restrict__ d4, short* __restrict__ d5,
    int n0, int n1, int n2, int n3, int n4, int n5)
{
    const int seg = blockIdx.y;
    const float* s = (seg == 0) ? s0 : (seg == 1) ? s1 : (seg == 2) ? s2
                   : (seg == 3) ? s3 : (seg == 4) ? s4 : s5;
    short* d = (seg == 0) ? d0 : (seg == 1) ? d1 : (seg == 2) ? d2
             : (seg == 3) ? d3 : (seg == 4) ? d4 : d5;
    const int n = (seg == 0) ? n0 : (seg == 1) ? n1 : (seg == 2) ? n2
                : (seg == 3) ? n3 : (seg == 4) ? n4 : n5;

    const int i = (blockIdx.x * 256 + threadIdx.x) * 8;
    if (i >= n) return;
    float4 a = *(const float4*)(s + i);
    float4 b = *(const float4*)(s + i + 4);
    uint4 u = { pkbf(a.x, a.y), pkbf(a.z, a.w), pkbf(b.x, b.y), pkbf(b.z, b.w) };
    *(uint4*)(d + i) = u;
}

// ---------------------------------------------------------------------------
// proj2: bf16 NT GEMM. 128x128 tile, BK=64, 4 waves x 64x64 quadrant.
// global_load_lds width=16 into UNPADDED LDS, XOR chunk swizzle (^ row&7).
// z==2 (V projection) writes the TRANSPOSED VT layout directly (kills vtrans).
// ---------------------------------------------------------------------------
__global__ __launch_bounds__(256, 3) void proj2_kernel(
    const short* __restrict__ Xq, const short* __restrict__ Xk, const short* __restrict__ Xv,
    const short* __restrict__ Wq, const short* __restrict__ Wk, const short* __restrict__ Wv,
    const float* __restrict__ bq, const float* __restrict__ bk, const float* __restrict__ bv,
    short* __restrict__ Oq, short* __restrict__ Ok, short* __restrict__ Ov)
{
    const int z = blockIdx.z;
    const short* X    = (z == 0) ? Xq : (z == 1) ? Xk : Xv;
    const short* W    = (z == 0) ? Wq : (z == 1) ? Wk : Wv;
    const float* bias = (z == 0) ? bq : (z == 1) ? bk : bv;
    short* Out        = (z == 0) ? Oq : (z == 1) ? Ok : Ov;
    const float osc   = (z == 0) ? QSCALE : 1.0f;

    const int n0 = blockIdx.x * 128;
    const int m0 = blockIdx.y * 128;

    __shared__ __align__(16) short As[128 * 64];
    __shared__ __align__(16) short Bs[128 * 64];

    const int t    = threadIdx.x;
    const int lane = t & 63;
    const int wave = t >> 6;
    const int r    = lane & 15;
    const int quad = lane >> 4;
    const int wm   = (wave >> 1) * 64;
    const int wn   = (wave & 1) * 64;

    const int p0    = wave * 256 + lane;
    const int row0  = p0 >> 3;
    const int lc0   = (p0 & 7) ^ (row0 & 7);
    const short* gA = X + (size_t)(m0 + row0) * EMB + lc0 * 8;
    const short* gB = W + (size_t)(n0 + row0) * EMB + lc0 * 8;
    short* lA = As + p0 * 8;
    short* lB = Bs + p0 * 8;

    f32x4 acc[4][4];
#pragma unroll
    for (int i = 0; i < 4; ++i)
#pragma unroll
        for (int j = 0; j < 4; ++j)
#pragma unroll
            for (int v = 0; v < 4; ++v) acc[i][j][v] = 0.f;

    for (int k0 = 0; k0 < EMB; k0 += 64) {
#pragma unroll
        for (int i = 0; i < 4; ++i) {
            gl_lds16(gA + k0 + (size_t)8 * i * EMB, lA + i * 512);
            gl_lds16(gB + k0 + (size_t)8 * i * EMB, lB + i * 512);
        }
        __syncthreads();

#pragma unroll
        for (int ks = 0; ks < 2; ++ks) {
            const int fc = ((ks * 4 + quad) ^ (r & 7)) * 8;
            s16x8 af[4], bf[4];
#pragma unroll
            for (int i = 0; i < 4; ++i) af[i] = *(const s16x8*)&As[(wm + i * 16 + r) * 64 + fc];
#pragma unroll
            for (int j = 0; j < 4; ++j) bf[j] = *(const s16x8*)&Bs[(wn + j * 16 + r) * 64 + fc];
#pragma unroll
            for (int i = 0; i < 4; ++i)
#pragma unroll
                for (int j = 0; j < 4; ++j)
                    acc[i][j] = __builtin_amdgcn_mfma_f32_16x16x32_bf16(af[i], bf[j], acc[i][j], 0, 0, 0);
        }
        __syncthreads();
    }

    if (z != 2) {
#pragma unroll
        for (int j = 0; j < 4; ++j) {
            const int gn = n0 + wn + j * 16 + r;
            const float bb = bias[gn];
#pragma unroll
            for (int i = 0; i < 4; ++i)
#pragma unroll
                for (int reg = 0; reg < 4; ++reg) {
                    const int gm = m0 + wm + i * 16 + quad * 4 + reg;
                    Out[(size_t)gm * EMB + gn] = bf16r((acc[i][j][reg] + bb) * osc);
                }
        }
    } else {
        // V: write VT[(b*16+h)*64+d][token] directly.  gn -> (h,d), gm -> (b,token).
#pragma unroll
        for (int j = 0; j < 4; ++j) {
            const int gn = n0 + wn + j * 16 + r;
            const float bb = bias[gn];
            const int hh = gn >> 6;
            const int dd = gn & 63;
#pragma unroll
            for (int i = 0; i < 4; ++i) {
                const int gm = m0 + wm + i * 16 + quad * 4;
                const int bi = gm >> 11;
                const int nn = gm & 2047;
                s16x4 pk;
#pragma unroll
                for (int reg = 0; reg < 4; ++reg) pk[reg] = bf16r(acc[i][j][reg] + bb);
                *(s16x4*)(Out + ((size_t)(bi * NHEAD + hh) * DHEAD + dd) * NSEQ + nn) = pk;
            }
        }
    }
}

// ---------------------------------------------------------------------------
// Fallback projection (fp32 inputs, convert during staging). Row-major outputs.
// ---------------------------------------------------------------------------
__global__ __launch_bounds__(256) void proj_kernel(
    const float* __restrict__ Xq, const float* __restrict__ Xk, const float* __restrict__ Xv,
    const float* __restrict__ Wq, const float* __restrict__ Wk, const float* __restrict__ Wv,
    const float* __restrict__ bq, const float* __restrict__ bk, const float* __restrict__ bv,
    short* __restrict__ Oq, short* __restrict__ Ok, short* __restrict__ Ov)
{
    const int z = blockIdx.z;
    const float* X    = (z == 0) ? Xq : (z == 1) ? Xk : Xv;
    const float* W    = (z == 0) ? Wq : (z == 1) ? Wk : Wv;
    const float* bias = (z == 0) ? bq : (z == 1) ? bk : bv;
    short* Out        = (z == 0) ? Oq : (z == 1) ? Ok : Ov;
    const float osc   = (z == 0) ? QSCALE : 1.0f;

    const int n0 = blockIdx.x * 128;
    const int m0 = blockIdx.y * 128;

    __shared__ __align__(16) short As[128][40];
    __shared__ __align__(16) short Bs[128][40];

    const int t    = threadIdx.x;
    const int lane = t & 63;
    const int wave = t >> 6;
    const int r    = lane & 15;
    const int quad = lane >> 4;
    const int wm   = (wave >> 1) * 64;
    const int wn   = (wave & 1) * 64;

    const int srow = t >> 1;
    const int scol = (t & 1) << 4;

    f32x4 acc[4][4];
#pragma unroll
    for (int i = 0; i < 4; ++i)
#pragma unroll
        for (int j = 0; j < 4; ++j)
#pragma unroll
            for (int v = 0; v < 4; ++v) acc[i][j][v] = 0.f;

    for (int k0 = 0; k0 < EMB; k0 += 32) {
        const float4* xp = (const float4*)(X + (size_t)(m0 + srow) * EMB + k0 + scol);
        const float4* wp = (const float4*)(W + (size_t)(n0 + srow) * EMB + k0 + scol);
        float4 x0 = xp[0], x1 = xp[1], x2 = xp[2], x3 = xp[3];
        float4 w0 = wp[0], w1 = wp[1], w2 = wp[2], w3 = wp[3];
        uint4 a0 = { pkbf(x0.x, x0.y), pkbf(x0.z, x0.w), pkbf(x1.x, x1.y), pkbf(x1.z, x1.w) };
        uint4 a1 = { pkbf(x2.x, x2.y), pkbf(x2.z, x2.w), pkbf(x3.x, x3.y), pkbf(x3.z, x3.w) };
        uint4 b0 = { pkbf(w0.x, w0.y), pkbf(w0.z, w0.w), pkbf(w1.x, w1.y), pkbf(w1.z, w1.w) };
        uint4 b1 = { pkbf(w2.x, w2.y), pkbf(w2.z, w2.w), pkbf(w3.x, w3.y), pkbf(w3.z, w3.w) };
        *(uint4*)&As[srow][scol]     = a0;
        *(uint4*)&As[srow][scol + 8] = a1;
        *(uint4*)&Bs[srow][scol]     = b0;
        *(uint4*)&Bs[srow][scol + 8] = b1;
        __syncthreads();

        s16x8 af[4], bf[4];
#pragma unroll
        for (int i = 0; i < 4; ++i) af[i] = *(const s16x8*)&As[wm + i * 16 + r][quad * 8];
#pragma unroll
        for (int j = 0; j < 4; ++j) bf[j] = *(const s16x8*)&Bs[wn + j * 16 + r][quad * 8];
#pragma unroll
        for (int i = 0; i < 4; ++i)
#pragma unroll
            for (int j = 0; j < 4; ++j)
                acc[i][j] = __builtin_amdgcn_mfma_f32_16x16x32_bf16(af[i], bf[j], acc[i][j], 0, 0, 0);
        __syncthreads();
    }

#pragma unroll
    for (int j = 0; j < 4; ++j) {
        const int gn = n0 + wn + j * 16 + r;
        const float bb = bias[gn];
#pragma unroll
        for (int i = 0; i < 4; ++i)
#pragma unroll
            for (int reg = 0; reg < 4; ++reg) {
                const int gm = m0 + wm + i * 16 + quad * 4 + reg;
                Out[(size_t)gm * EMB + gn] = bf16r((acc[i][j][reg] + bb) * osc);
            }
    }
}

// ---------------------------------------------------------------------------
// V transpose (fallback path only): V [b*2048+n][h*64+d] -> VT [(b*16+h)*64+d][n]
// ---------------------------------------------------------------------------
__global__ __launch_bounds__(256) void vtrans_kernel(
    const short* __restrict__ Vp, short* __restrict__ VT)
{
    const int n0 = blockIdx.x * 64;
    const int h  = blockIdx.y;
    const int b  = blockIdx.z;
    __shared__ __align__(16) short L[64][72];

    const int t  = threadIdx.x;
    const int rr = t >> 2;
    const int cc = (t & 3) * 16;

    const short* src = Vp + (size_t)(b * NSEQ + n0 + rr) * EMB + h * DHEAD + cc;
    s16x8 a = *(const s16x8*)src;
    s16x8 c = *(const s16x8*)(src + 8);
    *(s16x8*)&L[rr][cc]     = a;
    *(s16x8*)&L[rr][cc + 8] = c;
    __syncthreads();

    const int d  = t >> 2;
    const int c4 = (t & 3) * 16;
    short vals[16];
#pragma unroll
    for (int i = 0; i < 16; ++i) vals[i] = L[c4 + i][d];
    short* dst = VT + ((size_t)(b * NHEAD + h) * DHEAD + d) * NSEQ + n0 + c4;
    *(s16x8*)dst       = *(s16x8*)&vals[0];
    *(s16x8*)(dst + 8) = *(s16x8*)&vals[8];
}

// ---------------------------------------------------------------------------
// attn12: attn11 compute (verified formulas) with 2-PHASE DOUBLE-BUFFERED
// gl_lds pipeline (T3-minimum recipe): stage tile it+1 into buf^1 BEFORE
// computing tile it from buf; ONE __syncthreads per tile (its vmcnt(0) drain
// lands AFTER the ~2000-cy compute, so the prefetch latency is fully hidden).
// attn11's 1-phase schedule (stage -> barrier -> compute) paid the full load
// latency serially each tile and 2 barriers/tile.
// LDS 2x32KB = 64KB -> 2 blocks/CU (residency is pinned at 2 regardless —
// measured R0/R4/R5 — so dbuf costs nothing).  Grid back to 512, no key-split,
// no comb pass (split bought nothing at fixed residency, cost ~8us).
// (256,2): proven no-spill codegen.
// ---------------------------------------------------------------------------
__global__ __launch_bounds__(256, 2) void attn12_kernel(
    const short* __restrict__ Qp, const short* __restrict__ Kp,
    const short* __restrict__ VT, float* __restrict__ Out)
{
    const int qblk = blockIdx.x * 128;
    const int h    = blockIdx.y;
    const int b    = blockIdx.z;

    __shared__ __align__(16) char smem[65536];
    short* S    = (short*)smem;   // buf b at b*16384: Ks[128][64] ; Vs[64][128]
    float* fbuf = (float*)smem;   // [64][68] floats (union, epilogue)

    const int t    = threadIdx.x;
    const int lane = t & 63;
    const int w    = t >> 6;         // q-strip: rows qblk + w*32 + qs*16 + r
    const int r    = lane & 15;
    const int quad = lane >> 4;
    const int r7   = r & 7;

    const size_t rowbase = (size_t)b * NSEQ;
    const int    colbase = h * DHEAD;
    const size_t bh64    = (size_t)(b * NHEAD + h) * DHEAD;

    // Q B-fragments
    s16x8 qf[2][2];
#pragma unroll
    for (int qs = 0; qs < 2; ++qs)
#pragma unroll
        for (int ks = 0; ks < 2; ++ks)
            qf[qs][ks] = *(const s16x8*)(Qp + (rowbase + qblk + w * 32 + qs * 16 + r) * EMB
                                          + colbase + ks * 32 + quad * 8);

    f32x4 accO[2][4];
#pragma unroll
    for (int qs = 0; qs < 2; ++qs)
#pragma unroll
        for (int dt = 0; dt < 4; ++dt)
#pragma unroll
            for (int v = 0; v < 4; ++v) accO[qs][dt][v] = 0.f;
    float lsum[2] = {0.f, 0.f};
    const f32x4 zf = {0.f, 0.f, 0.f, 0.f};

    // --- gl_lds staging addresses (pre-swizzled global src, linear LDS dest).
    // K: LDS chunk p = i*256+t -> row = t>>3 + 32i, slot = t&7; slot s holds
    //    global chunk s^(row&7); row&7 is i-invariant (32 ≡ 0 mod 8).
    // V: LDS chunk p = i*256+t -> row = t>>4 + 16i, slot = t&15.
    const int krow0 = t >> 3;
    const int kgc   = ((t & 7) ^ (krow0 & 7)) * 8;
    const int vrow0 = t >> 4;
    const int vgc   = ((t & 15) ^ (vrow0 & 7)) * 8;
    const short* gKp = Kp + (rowbase + krow0) * EMB + colbase + kgc;
    const short* gVp = VT + (bh64 + vrow0) * NSEQ + vgc;

    // prologue: stage tile 0 into buf 0
    {
        short* SK = S;
        short* SV = S + 8192;
#pragma unroll
        for (int i = 0; i < 4; ++i) {
            gl_lds16(gKp + (size_t)i * 32 * EMB, SK + (i * 256 + t) * 8);
            gl_lds16(gVp + (size_t)i * 16 * NSEQ, SV + (i * 256 + t) * 8);
        }
        gKp += (size_t)128 * EMB;
        gVp += 128;
    }
    __syncthreads();   // tile 0 resident

    // read-side swizzled offsets (in shorts)
    const int kofs = (quad ^ r7) * 8;
    int vofs[4];
    {
        const int x4  = r7 & 4;
        const int qr3 = ((quad >> 1) ^ r7) & 3;
#pragma unroll
        for (int s = 0; s < 4; ++s)
            vofs[s] = ((((s << 2) ^ x4) | qr3) * 8) + (quad & 1) * 4;
    }

#pragma unroll 2
    for (int it = 0; it < 16; ++it) {
        const int cur = it & 1;

        // stage tile it+1 into the OTHER buffer — in flight during compute
        if (it + 1 < 16) {
            short* SKn = S + (cur ^ 1) * 16384;
            short* SVn = SKn + 8192;
#pragma unroll
            for (int i = 0; i < 4; ++i) {
                gl_lds16(gKp + (size_t)i * 32 * EMB, SKn + (i * 256 + t) * 8);
                gl_lds16(gVp + (size_t)i * 16 * NSEQ, SVn + (i * 256 + t) * 8);
            }
            gKp += (size_t)128 * EMB;
            gVp += 128;
        }

        const short* Ks = S + cur * 16384;
        const short* Vs = Ks + 8192;

        // S^T = K Q^T per key-strip pair; exp2; pack PV B-fragments pf[qs][s]
        s16x8 pf[2][4];
#pragma unroll
        for (int s = 0; s < 4; ++s) {
            const short* kb = Ks + (s * 32 + r) * 64;
            const s16x8 kf00 = *(const s16x8*)(kb + kofs);
            const s16x8 kf01 = *(const s16x8*)(kb + (kofs ^ 32));
            const s16x8 kf10 = *(const s16x8*)(kb + 1024 + kofs);
            const s16x8 kf11 = *(const s16x8*)(kb + 1024 + (kofs ^ 32));
#pragma unroll
            for (int qs = 0; qs < 2; ++qs) {
                __builtin_amdgcn_s_setprio(1);
                f32x4 s0 = __builtin_amdgcn_mfma_f32_16x16x32_bf16(
                    kf01, qf[qs][1], __builtin_amdgcn_mfma_f32_16x16x32_bf16(kf00, qf[qs][0], zf, 0, 0, 0), 0, 0, 0);
                f32x4 s1 = __builtin_amdgcn_mfma_f32_16x16x32_bf16(
                    kf11, qf[qs][1], __builtin_amdgcn_mfma_f32_16x16x32_bf16(kf10, qf[qs][0], zf, 0, 0, 0), 0, 0, 0);
                __builtin_amdgcn_s_setprio(0);
                float p0[4], p1[4];
#pragma unroll
                for (int reg = 0; reg < 4; ++reg) {
                    p0[reg] = fexp2(s0[reg]);
                    p1[reg] = fexp2(s1[reg]);
                    lsum[qs] += p0[reg] + p1[reg];
                }
                uint4 uu = { pkbf(p0[0], p0[1]), pkbf(p0[2], p0[3]),
                             pkbf(p1[0], p1[1]), pkbf(p1[2], p1[3]) };
                __builtin_memcpy(&pf[qs][s], &uu, 16);
            }
        }

        // O^T += V^T P
#pragma unroll
        for (int dt = 0; dt < 4; ++dt) {
            const short* vb = Vs + (dt * 16 + r) * 128;
            s16x8 vfl[4];
#pragma unroll
            for (int s = 0; s < 4; ++s) {
                s16x4 lo = *(const s16x4*)(vb + vofs[s]);
                s16x4 hi = *(const s16x4*)(vb + (vofs[s] ^ 16));
                vfl[s] = __builtin_shufflevector(lo, hi, 0, 1, 2, 3, 4, 5, 6, 7);
            }
            __builtin_amdgcn_s_setprio(1);
#pragma unroll
            for (int qs = 0; qs < 2; ++qs)
#pragma unroll
                for (int s = 0; s < 4; ++s)
                    accO[qs][dt] = __builtin_amdgcn_mfma_f32_16x16x32_bf16(vfl[s], pf[qs][s], accO[qs][dt], 0, 0, 0);
            __builtin_amdgcn_s_setprio(0);
        }

        // ONE barrier per tile: drains the prefetch (already covered by the
        // compute above) and marks all reads of buf[cur] complete.
        __syncthreads();
    }

    // row sums
    float rl[2];
#pragma unroll
    for (int qs = 0; qs < 2; ++qs) {
        float s = lsum[qs];
        s += __shfl_xor(s, 16);
        s += __shfl_xor(s, 32);
        rl[qs] = 1.f / s;
    }

    // Epilogue: O^T (rows=d, cols=q) -> fbuf[q][d] -> coalesced f32x4 stores
#pragma unroll
    for (int qs = 0; qs < 2; ++qs) {
        __syncthreads();
#pragma unroll
        for (int dt = 0; dt < 4; ++dt)
#pragma unroll
            for (int reg = 0; reg < 4; ++reg)
                fbuf[(w * 16 + r) * 68 + dt * 16 + quad * 4 + reg] = accO[qs][dt][reg] * rl[qs];
        __syncthreads();
        const int qi   = t >> 2;
        const int c    = (t & 3) * 16;
        const int wsrc = qi >> 4;
        const int rsrc = qi & 15;
        const float4* fp = (const float4*)&fbuf[(wsrc * 16 + rsrc) * 68 + c];
        float4 o0 = fp[0], o1 = fp[1], o2 = fp[2], o3 = fp[3];
        float* op = Out + (rowbase + qblk + wsrc * 32 + qs * 16 + rsrc) * EMB + colbase + c;
        ((float4*)op)[0] = o0;
        ((float4*)op)[1] = o1;
        ((float4*)op)[2] = o2;
        ((float4*)op)[3] = o3;
    }
}

// ---------------------------------------------------------------------------
// Fallback attention (round-1 structure) for small ws.
// ---------------------------------------------------------------------------
__global__ __launch_bounds__(256) void attn_fb_kernel(
    const short* __restrict__ Qp, const short* __restrict__ Kp,
    const short* __restrict__ Vp, float* __restrict__ Out)
{
    const int qt = blockIdx.x;
    const int h  = blockIdx.y;
    const int b  = blockIdx.z;

    __shared__ __align__(16) short Ks[64][72];
    __shared__ __align__(16) short VsT[64][72];
    __shared__ __align__(16) short Ps[4][16][72];

    const int t    = threadIdx.x;
    const int lane = t & 63;
    const int w    = t >> 6;
    const int r    = lane & 15;
    const int quad = lane >> 4;

    const size_t rowbase = (size_t)b * NSEQ;
    const int colbase    = h * DHEAD;

    const short* Qr = Qp + (rowbase + qt * 64 + w * 16 + r) * EMB + colbase;
    const s16x8 qf0 = *(const s16x8*)(Qr + quad * 8);
    const s16x8 qf1 = *(const s16x8*)(Qr + 32 + quad * 8);

    float mrow[4], lrow[4];
    f32x4 accO[4];
#pragma unroll
    for (int i = 0; i < 4; ++i) {
        mrow[i] = -INFINITY;
        lrow[i] = 0.f;
#pragma unroll
        for (int v = 0; v < 4; ++v) accO[i][v] = 0.f;
    }

    const int srow = t >> 2;
    const int scol = (t & 3) << 4;

    for (int kt = 0; kt < 32; ++kt) {
        const short* Krow = Kp + (rowbase + kt * 64 + srow) * EMB + colbase + scol;
        const short* Vrow = Vp + (rowbase + kt * 64 + srow) * EMB + colbase + scol;
        s16x8 kv0 = *(const s16x8*)Krow;
        s16x8 kv1 = *(const s16x8*)(Krow + 8);
        s16x8 vv0 = *(const s16x8*)Vrow;
        s16x8 vv1 = *(const s16x8*)(Vrow + 8);
        *(s16x8*)&Ks[srow][scol]     = kv0;
        *(s16x8*)&Ks[srow][scol + 8] = kv1;
#pragma unroll
        for (int i = 0; i < 8; ++i) {
            VsT[scol + i][srow]     = vv0[i];
            VsT[scol + 8 + i][srow] = vv1[i];
        }
        __syncthreads();

        f32x4 sacc[4];
#pragma unroll
        for (int j = 0; j < 4; ++j) {
#pragma unroll
            for (int v = 0; v < 4; ++v) sacc[j][v] = 0.f;
            s16x8 kf0 = *(const s16x8*)&Ks[j * 16 + r][quad * 8];
            s16x8 kf1 = *(const s16x8*)&Ks[j * 16 + r][32 + quad * 8];
            sacc[j] = __builtin_amdgcn_mfma_f32_16x16x32_bf16(qf0, kf0, sacc[j], 0, 0, 0);
            sacc[j] = __builtin_amdgcn_mfma_f32_16x16x32_bf16(qf1, kf1, sacc[j], 0, 0, 0);
        }

        float rmax[4];
#pragma unroll
        for (int reg = 0; reg < 4; ++reg) rmax[reg] = -INFINITY;
#pragma unroll
        for (int j = 0; j < 4; ++j)
#pragma unroll
            for (int reg = 0; reg < 4; ++reg)
                rmax[reg] = fmaxf(rmax[reg], sacc[j][reg]);
#pragma unroll
        for (int reg = 0; reg < 4; ++reg) {
#pragma unroll
            for (int mask = 1; mask <= 8; mask <<= 1)
                rmax[reg] = fmaxf(rmax[reg], __shfl_xor(rmax[reg], mask, 64));
        }

        float alpha[4], rsum[4];
#pragma unroll
        for (int reg = 0; reg < 4; ++reg) {
            float mnew = fmaxf(mrow[reg], rmax[reg]);
            alpha[reg] = fexp2(mrow[reg] - mnew);
            mrow[reg]  = mnew;
            rsum[reg]  = 0.f;
        }

#pragma unroll
        for (int j = 0; j < 4; ++j)
#pragma unroll
            for (int reg = 0; reg < 4; ++reg) {
                float p = fexp2(sacc[j][reg] - mrow[reg]);
                rsum[reg] += p;
                Ps[w][quad * 4 + reg][j * 16 + r] = bf16r(p);
            }
#pragma unroll
        for (int reg = 0; reg < 4; ++reg) {
#pragma unroll
            for (int mask = 1; mask <= 8; mask <<= 1)
                rsum[reg] += __shfl_xor(rsum[reg], mask, 64);
            lrow[reg] = lrow[reg] * alpha[reg] + rsum[reg];
        }
#pragma unroll
        for (int j = 0; j < 4; ++j)
#pragma unroll
            for (int reg = 0; reg < 4; ++reg) accO[j][reg] *= alpha[reg];

#pragma unroll
        for (int s = 0; s < 2; ++s) {
            s16x8 pfr = *(const s16x8*)&Ps[w][r][s * 32 + quad * 8];
#pragma unroll
            for (int j = 0; j < 4; ++j) {
                s16x8 vfr = *(const s16x8*)&VsT[j * 16 + r][s * 32 + quad * 8];
                accO[j] = __builtin_amdgcn_mfma_f32_16x16x32_bf16(pfr, vfr, accO[j], 0, 0, 0);
            }
        }
        __syncthreads();
    }

#pragma unroll
    for (int j = 0; j < 4; ++j)
#pragma unroll
        for (int reg = 0; reg < 4; ++reg) {
            const int qrow = qt * 64 + w * 16 + quad * 4 + reg;
            Out[(rowbase + qrow) * EMB + colbase + j * 16 + r] = accO[j][reg] / lrow[reg];
        }
}

extern "C" void kernel_launch(void* const* d_in, const int* in_sizes, int n_in,
                              void* d_out, int out_size, void* d_ws, size_t ws_size,
                              hipStream_t stream) {
    const float* query = (const float*)d_in[0];
    const float* key   = (const float*)d_in[1];
    const float* value = (const float*)d_in[2];
    const float* Wq    = (const float*)d_in[3];
    const float* bq    = (const float*)d_in[4];
    const float* Wk    = (const float*)d_in[5];
    const float* bk    = (const float*)d_in[6];
    const float* Wv    = (const float*)d_in[7];
    const float* bv    = (const float*)d_in[8];
    float* out = (float*)d_out;

    const size_t XBUF = (size_t)NBATCH * NSEQ * EMB;   // 4 Mi elements
    const size_t WBUF = (size_t)EMB * EMB;

    short* Qb  = (short*)d_ws;
    short* Kb  = Qb + XBUF;
    short* Vb  = Kb + XBUF;
    short* VTb = Vb + XBUF;
    short* Xqb = VTb + XBUF;
    short* Xkb = Xqb + XBUF;
    short* Xvb = Xkb + XBUF;
    short* Wqb = Xvb + XBUF;
    short* Wkb = Wqb + WBUF;
    short* Wvb = Wkb + WBUF;

    const size_t need_full = (7 * XBUF + 3 * WBUF) * sizeof(short);
    const size_t need_attn = 4 * XBUF * sizeof(short);

    if (ws_size >= need_full) {
        cvt6_kernel<<<dim3(2048, 6), 256, 0, stream>>>(
            query, key, value, Wq, Wk, Wv,
            Xqb, Xkb, Xvb, Wqb, Wkb, Wvb,
            (int)XBUF, (int)XBUF, (int)XBUF, (int)WBUF, (int)WBUF, (int)WBUF);
        // z==2 writes VTb (transposed) directly — no vtrans pass
        proj2_kernel<<<dim3(EMB / 128, (NBATCH * NSEQ) / 128, 3), 256, 0, stream>>>(
            Xqb, Xkb, Xvb, Wqb, Wkb, Wvb, bq, bk, bv, Qb, Kb, VTb);
        attn12_kernel<<<dim3(NSEQ / 128, NHEAD, NBATCH), 256, 0, stream>>>(
            Qb, Kb, VTb, out);
    } else if (ws_size >= need_attn) {
        proj_kernel<<<dim3(EMB / 128, (NBATCH * NSEQ) / 128, 3), 256, 0, stream>>>(
            query, key, value, Wq, Wk, Wv, bq, bk, bv, Qb, Kb, Vb);
        vtrans_kernel<<<dim3(NSEQ / 64, NHEAD, NBATCH), 256, 0, stream>>>(Vb, VTb);
        attn12_kernel<<<dim3(NSEQ / 128, NHEAD, NBATCH), 256, 0, stream>>>(
            Qb, Kb, VTb, out);
    } else {
        proj_kernel<<<dim3(EMB / 128, (NBATCH * NSEQ) / 128, 3), 256, 0, stream>>>(
            query, key, value, Wq, Wk, Wv, bq, bk, bv, Qb, Kb, Vb);
        attn_fb_kernel<<<dim3(NSEQ / 64, NHEAD, NBATCH), 256, 0, stream>>>(Qb, Kb, Vb, out);
    }
}